// Round 16
// baseline (2436.201 us; speedup 1.0000x reference)
//
#include <hip/hip_runtime.h>
#include <math.h>

#define SEQ 96
#define EMB 768
#define G4  3072   // 4*H
#define NLAYER 95  // conv layers
#define CKP 264    // xs col pitch (bf16 elems): 256 k-chunk + 8 pad
#define CONV_WG 48
#define LSTM_WG 192
#define NREP 32      // epoch replica lines
#define XPITCH 1536  // ushorts per col in x buffers: 48 blocks x (hi16|lo16)
#define WB_BYTES 225345536ull   // ws bytes needed for bf16 weight planes path

typedef float  f32x4  __attribute__((ext_vector_type(4)));
typedef short  bf16x8 __attribute__((ext_vector_type(8)));
typedef unsigned long long ull;

union BF8 { unsigned short u[8]; bf16x8 v; };

__device__ __forceinline__ unsigned short f2bf(float f) {   // RNE fp32->bf16
    unsigned u = __float_as_uint(f);
    u += 0x7FFFu + ((u >> 16) & 1u);
    return (unsigned short)(u >> 16);
}
__device__ __forceinline__ float bf2f(unsigned short u) {
    return __uint_as_float(((unsigned)u) << 16);
}

// ---- sc1 (LLC-direct, coherent) loads/stores for cross-WG mutable data ---
__device__ __forceinline__ ull ld64g(const void* p) {
    return __hip_atomic_load((const ull*)p, __ATOMIC_RELAXED,
                             __HIP_MEMORY_SCOPE_AGENT);
}
__device__ __forceinline__ void st32g(void* p, unsigned v) {
    __hip_atomic_store((unsigned*)p, v, __ATOMIC_RELAXED,
                       __HIP_MEMORY_SCOPE_AGENT);
}
__device__ __forceinline__ void stf32g(float* p, float v) {
    __hip_atomic_store((unsigned*)p, __float_as_uint(v), __ATOMIC_RELAXED,
                       __HIP_MEMORY_SCOPE_AGENT);
}
__device__ __forceinline__ unsigned ldflag(const unsigned* p) {
    return __hip_atomic_load(p, __ATOMIC_RELAXED, __HIP_MEMORY_SCOPE_AGENT);
}
__device__ __forceinline__ void stflag(unsigned* p, unsigned v) {
    __hip_atomic_store(p, v, __ATOMIC_RELAXED, __HIP_MEMORY_SCOPE_AGENT);
}

// ------ grid barrier: sc1 flags, 32 epoch replicas, NO invalidates --------
__device__ __forceinline__ void relbar(unsigned* flags, unsigned* epoch,
                                       int nwg, int wg, unsigned target) {
    asm volatile("s_waitcnt vmcnt(0)" ::: "memory");
    __syncthreads();
    if (threadIdx.x == 0) stflag(&flags[wg * 16], target);
    if (wg == 0) {
        if ((int)threadIdx.x < nwg)
            while (ldflag(&flags[threadIdx.x * 16]) < target)
                __builtin_amdgcn_s_sleep(2);
        __syncthreads();
        if (threadIdx.x < NREP) stflag(&epoch[threadIdx.x * 16], target);
    }
    if (threadIdx.x == 0) {
        const unsigned* ep = &epoch[(wg & (NREP - 1)) * 16];
        while (ldflag(ep) < target)
            __builtin_amdgcn_s_sleep(8);
    }
    asm volatile("" ::: "memory");
    __syncthreads();
}

__device__ __forceinline__ float red16(float a) {
    a += __shfl_xor(a, 8, 16);
    a += __shfl_xor(a, 4, 16);
    a += __shfl_xor(a, 2, 16);
    a += __shfl_xor(a, 1, 16);
    return a;
}

__device__ __forceinline__ float sigmoidf_(float x) {
    return 1.0f / (1.0f + __expf(-x));
}

// ---- weight prep: fp32 interleaved (w0,w1) -> bf16 planes wb0, wb1 -------
__global__ void k_prep(const float* __restrict__ w,
                       unsigned short* __restrict__ wb0,
                       unsigned short* __restrict__ wb1) {
    const size_t p0 = ((size_t)blockIdx.x * 256 + threadIdx.x) * 4;
    const f32x4* src = (const f32x4*)(w + p0 * 2);
    f32x4 f0 = __builtin_nontemporal_load(src);
    f32x4 f1 = __builtin_nontemporal_load(src + 1);
    ushort4 a, b;
    a.x = f2bf(f0.x); b.x = f2bf(f0.y);
    a.y = f2bf(f0.z); b.y = f2bf(f0.w);
    a.z = f2bf(f1.x); b.z = f2bf(f1.y);
    a.w = f2bf(f1.z); b.w = f2bf(f1.w);
    *(ushort4*)(wb0 + p0) = a;
    *(ushort4*)(wb1 + p0) = b;
}

// ---------------- emb2 gather -> hi/lo bf16 x0 ----------------------------
__global__ void k_embed(const int* __restrict__ xids,
                        const float* __restrict__ emb2,
                        unsigned short* __restrict__ x0) {
    const int col = blockIdx.x;                 // 96 blocks
    const int tok = xids[col];
    const int tid = threadIdx.x;
    if (tid < 192) {
        float4 v = *(const float4*)(emb2 + (size_t)tok * EMB + tid * 4);
        ushort4 hv, lv;
        hv.x = f2bf(v.x); lv.x = f2bf(v.x - bf2f(hv.x));
        hv.y = f2bf(v.y); lv.y = f2bf(v.y - bf2f(hv.y));
        hv.z = f2bf(v.z); lv.z = f2bf(v.z - bf2f(hv.z));
        hv.w = f2bf(v.w); lv.w = f2bf(v.w - bf2f(hv.w));
        unsigned short* base = x0 + col * XPITCH + (tid >> 2) * 32 + (tid & 3) * 4;
        *(ushort4*)base        = hv;
        *(ushort4*)(base + 16) = lv;
    }
}

// ---- issue one layer's 16-row bf16 weight slab (12 x bf16x8, cached) -----
#define ISSUE_W_B16(LAY, W0R, W1R) do {                                      \
    const unsigned short* w0_ = wb0 + ((size_t)(LAY) * EMB + r0 + lj) * EMB; \
    const unsigned short* w1_ = wb1 + ((size_t)(LAY) * EMB + r0 + lj) * EMB; \
    _Pragma("unroll")                                                        \
    for (int ch_ = 0; ch_ < 3; ++ch_) {                                      \
        _Pragma("unroll")                                                    \
        for (int s_ = 0; s_ < 2; ++s_) {                                     \
            const int k_ = (ch_ * 8 + wv * 2 + s_) * 32 + lg * 8;            \
            W0R[ch_][s_] = *(const bf16x8*)(w0_ + k_);                       \
            W1R[ch_][s_] = *(const bf16x8*)(w1_ + k_);                       \
        }                                                                    \
    }                                                                        \
} while (0)

// ---- conv barrier tail, NO prefetch (b16 path prefetches early) ----------
#define CONV_BARRIER_NP(LAY) do {                                            \
    if ((LAY) + 1 < NLAYER) {                                                \
        const unsigned tgt = (unsigned)((LAY) + 1);                          \
        asm volatile("s_waitcnt vmcnt(0)" ::: "memory");                     \
        __syncthreads();                                                     \
        if (tid == 0) stflag(&cflags[bI * 16], tgt);                         \
        if (bI == 0) {                                                       \
            if (tid < CONV_WG)                                               \
                while (ldflag(&cflags[tid * 16]) < tgt)                      \
                    __builtin_amdgcn_s_sleep(2);                             \
            __syncthreads();                                                 \
            if (tid < NREP) stflag(&cepoch[tid * 16], tgt);                  \
        }                                                                    \
        if (tid == 0) {                                                      \
            const unsigned* ep = &cepoch[(bI & (NREP - 1)) * 16];            \
            while (ldflag(ep) < tgt)                                         \
                __builtin_amdgcn_s_sleep(8);                                 \
        }                                                                    \
        asm volatile("" ::: "memory");                                       \
        __syncthreads();                                                     \
    }                                                                        \
} while (0)

// ---- conv barrier tail with prefetch hook (f32 fallback path) ------------
#define CONV_BARRIER(LAY, PREFETCH) do {                                     \
    if ((LAY) + 1 < NLAYER) {                                                \
        const unsigned tgt = (unsigned)((LAY) + 1);                          \
        asm volatile("s_waitcnt vmcnt(0)" ::: "memory");                     \
        __syncthreads();                                                     \
        if (tid == 0) stflag(&cflags[bI * 16], tgt);                         \
        PREFETCH;                                                            \
        asm volatile("" ::: "memory");                                       \
        if (bI == 0) {                                                       \
            if (tid < CONV_WG)                                               \
                while (ldflag(&cflags[tid * 16]) < tgt)                      \
                    __builtin_amdgcn_s_sleep(2);                             \
            __syncthreads();                                                 \
            if (tid < NREP) stflag(&cepoch[tid * 16], tgt);                  \
        }                                                                    \
        if (tid == 0) {                                                      \
            const unsigned* ep = &cepoch[(bI & (NREP - 1)) * 16];            \
            while (ldflag(ep) < tgt)                                         \
                __builtin_amdgcn_s_sleep(8);                                 \
        }                                                                    \
        asm volatile("" ::: "memory");                                       \
        __syncthreads();                                                     \
    }                                                                        \
} while (0)

// ---- epilogue: K-split reduce + relu + packed hi/lo sc1 store ------------
#define CONV_EPILOGUE(LAY) do {                                              \
    _Pragma("unroll")                                                        \
    for (int nt = 0; nt < 6; ++nt) if (nt < nts)                             \
        *(f32x4*)&part[wv * 1536 + (nt * 16 + lj) * 16 + lg * 4] = acc[nt];  \
    __syncthreads();                                                         \
    _Pragma("unroll")                                                        \
    for (int j = 0; j < 3; ++j) {                                            \
        const int o2 = tid + j * 256;                                        \
        const int c = o2 >> 3, p = o2 & 7;                                   \
        if (c < ncols) {                                                     \
            const int i0 = p * 2;                                            \
            const int oo = c * 16 + i0;                                      \
            float s0 = part[oo] + part[1536 + oo] + part[3072 + oo]          \
                     + part[4608 + oo] + conv_b[(LAY) * EMB + r0 + i0];      \
            float s1 = part[oo + 1] + part[1537 + oo] + part[3073 + oo]      \
                     + part[4609 + oo] + conv_b[(LAY) * EMB + r0 + i0 + 1];  \
            s0 = fmaxf(s0, 0.f); s1 = fmaxf(s1, 0.f);                        \
            const unsigned short h0 = f2bf(s0), h1 = f2bf(s1);               \
            const unsigned short l0 = f2bf(s0 - bf2f(h0));                   \
            const unsigned short l1 = f2bf(s1 - bf2f(h1));                   \
            unsigned short* dp = dst + c * XPITCH + bI * 32 + i0;            \
            st32g(dp,      (unsigned)h0 | ((unsigned)h1 << 16));             \
            st32g(dp + 16, (unsigned)l0 | ((unsigned)l1 << 16));             \
            if ((LAY) == NLAYER - 1 && c == 0) {                             \
                dout[3074 + r0 + i0]     = s0;                               \
                dout[3074 + r0 + i0 + 1] = s1;                               \
            }                                                                \
        }                                                                    \
    }                                                                        \
} while (0)

// ---- x-chunk restage: batched sc1 loads (24x8B in flight) -> LDS ---------
#define STAGE_X(CH) do {                                                     \
    _Pragma("unroll")                                                        \
    for (int jj = 0; jj < 2; ++jj) {                                         \
        ull Rst[6][4];                                                       \
        _Pragma("unroll")                                                    \
        for (int j = 0; j < 6; ++j) {                                        \
            const int u = tid + (jj * 6 + j) * 256;                          \
            const int c = u >> 5, q = u & 31;                                \
            if (c < scols) {                                                 \
                const int k = (CH) * 256 + q * 8;                            \
                const unsigned short* sp =                                   \
                    src + c * XPITCH + ((k >> 4) << 5) + (k & 15);           \
                Rst[j][0] = ld64g(sp);                                       \
                Rst[j][1] = ld64g(sp + 4);                                   \
                Rst[j][2] = ld64g(sp + 16);                                  \
                Rst[j][3] = ld64g(sp + 20);                                  \
            }                                                                \
        }                                                                    \
        _Pragma("unroll")                                                    \
        for (int j = 0; j < 6; ++j) {                                        \
            const int u = tid + (jj * 6 + j) * 256;                          \
            const int c = u >> 5, q = u & 31;                                \
            if (c < scols) {                                                 \
                *(ull*)(xs_hi + c * CKP + q * 8)     = Rst[j][0];            \
                *(ull*)(xs_hi + c * CKP + q * 8 + 4) = Rst[j][1];            \
                *(ull*)(xs_lo + c * CKP + q * 8)     = Rst[j][2];            \
                *(ull*)(xs_lo + c * CKP + q * 8 + 4) = Rst[j][3];            \
            }                                                                \
        }                                                                    \
    }                                                                        \
} while (0)

// ---- one chunk's MFMA work, bf16 weight regs -----------------------------
#define CONV_CHUNK_B16(CH, W0c, W1c) do {                                    \
    _Pragma("unroll")                                                        \
    for (int s = 0; s < 2; ++s) {                                            \
        const bf16x8 a0 = W0c[CH][s];                                        \
        const bf16x8 a1 = W1c[CH][s];                                        \
        const int klocal = (wv * 2 + s) * 32;                                \
        _Pragma("unroll")                                                    \
        for (int nt = 0; nt < 6; ++nt) if (nt < nts) {                       \
            const int co = (nt * 16 + lj) * CKP + klocal + lg * 8;           \
            bf16x8 bh0 = *(const bf16x8*)(xs_hi + co);                       \
            bf16x8 bl0 = *(const bf16x8*)(xs_lo + co);                       \
            bf16x8 bh1 = *(const bf16x8*)(xs_hi + co + CKP);                 \
            bf16x8 bl1 = *(const bf16x8*)(xs_lo + co + CKP);                 \
            acc[nt] = __builtin_amdgcn_mfma_f32_16x16x32_bf16(               \
                          a0, bh0, acc[nt], 0, 0, 0);                        \
            acc[nt] = __builtin_amdgcn_mfma_f32_16x16x32_bf16(               \
                          a0, bl0, acc[nt], 0, 0, 0);                        \
            acc[nt] = __builtin_amdgcn_mfma_f32_16x16x32_bf16(               \
                          a1, bh1, acc[nt], 0, 0, 0);                        \
            acc[nt] = __builtin_amdgcn_mfma_f32_16x16x32_bf16(               \
                          a1, bl1, acc[nt], 0, 0, 0);                        \
        }                                                                    \
    }                                                                        \
} while (0)

// ---- full conv layer, bf16 planes; EARLY prefetch of layer L+1 weights ---
#define CONV_LAYER_B16(LAY, W0c, W1c, W0n, W1n) do {                         \
    const int ncols = NLAYER - (LAY);                                        \
    const int scols = (ncols + 1 < 96) ? ncols + 1 : 96;                     \
    const int nts   = (ncols + 15) >> 4;                                     \
    const unsigned short* src = ((LAY) & 1) ? x1buf : x0buf;                 \
    unsigned short*       dst = ((LAY) & 1) ? x0buf : x1buf;                 \
    f32x4 acc[6];                                                            \
    _Pragma("unroll")                                                        \
    for (int n = 0; n < 6; ++n) acc[n] = (f32x4)0.f;                         \
    STAGE_X(0);                                                              \
    __syncthreads();                                                         \
    if ((LAY) + 1 < NLAYER) {      /* issue next-layer W loads NOW: */       \
        ISSUE_W_B16((LAY) + 1, W0n, W1n);   /* ~12us to land vs ~2us */      \
    }                                                                        \
    asm volatile("" ::: "memory");                                           \
    CONV_CHUNK_B16(0, W0c, W1c);                                             \
    __syncthreads();                                                         \
    STAGE_X(1);                                                              \
    __syncthreads();                                                         \
    CONV_CHUNK_B16(1, W0c, W1c);                                             \
    __syncthreads();                                                         \
    STAGE_X(2);                                                              \
    __syncthreads();                                                         \
    CONV_CHUNK_B16(2, W0c, W1c);                                             \
    __syncthreads();                                                         \
    CONV_EPILOGUE(LAY);                                                      \
    CONV_BARRIER_NP(LAY);                                                    \
} while (0)

// ---- fp32 fallback path: weight slab in float4 regs ----------------------
#define ISSUE_W_F32(LAY, WREG) do {                                          \
    const float* wsl_ = conv_w + (size_t)(LAY) * (EMB * EMB * 2)             \
                               + (size_t)(r0 + lj) * (EMB * 2);              \
    _Pragma("unroll")                                                        \
    for (int ch_ = 0; ch_ < 3; ++ch_) {                                      \
        _Pragma("unroll")                                                    \
        for (int s_ = 0; s_ < 2; ++s_) {                                     \
            const int K0_ = (ch_ * 8 + wv * 2 + s_) * 32;                    \
            const float4* ap_ =                                              \
                (const float4*)(wsl_ + (size_t)(K0_ + lg * 8) * 2);          \
            _Pragma("unroll")                                                \
            for (int j_ = 0; j_ < 4; ++j_) WREG[ch_][s_][j_] = ap_[j_];      \
        }                                                                    \
    }                                                                        \
} while (0)

#define CONV_LAYER_F32(LAY, Wc, Wn) do {                                     \
    const int ncols = NLAYER - (LAY);                                        \
    const int scols = (ncols + 1 < 96) ? ncols + 1 : 96;                     \
    const int nts   = (ncols + 15) >> 4;                                     \
    const unsigned short* src = ((LAY) & 1) ? x1buf : x0buf;                 \
    unsigned short*       dst = ((LAY) & 1) ? x0buf : x1buf;                 \
    f32x4 acc[6];                                                            \
    _Pragma("unroll")                                                        \
    for (int n = 0; n < 6; ++n) acc[n] = (f32x4)0.f;                         \
    _Pragma("unroll")                                                        \
    for (int ch = 0; ch < 3; ++ch) {                                         \
        STAGE_X(ch);                                                         \
        __syncthreads();                                                     \
        _Pragma("unroll")                                                    \
        for (int s = 0; s < 2; ++s) {                                        \
            const int klocal = (wv * 2 + s) * 32;                            \
            BF8 a0h, a0l, a1h, a1l;                                          \
            _Pragma("unroll")                                                \
            for (int d = 0; d < 8; ++d) {                                    \
                const float4 f = Wc[ch][s][d >> 1];                          \
                const float w0 = (d & 1) ? f.z : f.x;                        \
                const float w1 = (d & 1) ? f.w : f.y;                        \
                const unsigned short h0 = f2bf(w0);                          \
                const unsigned short h1 = f2bf(w1);                          \
                a0h.u[d] = h0; a0l.u[d] = f2bf(w0 - bf2f(h0));               \
                a1h.u[d] = h1; a1l.u[d] = f2bf(w1 - bf2f(h1));               \
            }                                                                \
            _Pragma("unroll")                                                \
            for (int nt = 0; nt < 6; ++nt) if (nt < nts) {                   \
                const int co = (nt * 16 + lj) * CKP + klocal + lg * 8;       \
                bf16x8 bh0 = *(const bf16x8*)(xs_hi + co);                   \
                bf16x8 bl0 = *(const bf16x8*)(xs_lo + co);                   \
                bf16x8 bh1 = *(const bf16x8*)(xs_hi + co + CKP);             \
                bf16x8 bl1 = *(const bf16x8*)(xs_lo + co + CKP);             \
                acc[nt] = __builtin_amdgcn_mfma_f32_16x16x32_bf16(           \
                              a0h.v, bh0, acc[nt], 0, 0, 0);                 \
                acc[nt] = __builtin_amdgcn_mfma_f32_16x16x32_bf16(           \
                              a0h.v, bl0, acc[nt], 0, 0, 0);                 \
                acc[nt] = __builtin_amdgcn_mfma_f32_16x16x32_bf16(           \
                              a0l.v, bh0, acc[nt], 0, 0, 0);                 \
                acc[nt] = __builtin_amdgcn_mfma_f32_16x16x32_bf16(           \
                              a1h.v, bh1, acc[nt], 0, 0, 0);                 \
                acc[nt] = __builtin_amdgcn_mfma_f32_16x16x32_bf16(           \
                              a1h.v, bl1, acc[nt], 0, 0, 0);                 \
                acc[nt] = __builtin_amdgcn_mfma_f32_16x16x32_bf16(           \
                              a1l.v, bh1, acc[nt], 0, 0, 0);                 \
            }                                                                \
        }                                                                    \
        __syncthreads();                                                     \
    }                                                                        \
    CONV_EPILOGUE(LAY);                                                      \
    CONV_BARRIER(LAY, ISSUE_W_F32((LAY) + 1, Wn));                           \
} while (0)

// ---------------- fused persistent kernel: 48 conv WGs + 192 LSTM WGs -----
__global__ __launch_bounds__(256, 1) void k_net(
    const int use_b16,
    const int* __restrict__ xids, const float* __restrict__ emb1,
    const float* __restrict__ conv_w, const float* __restrict__ conv_b,
    const unsigned short* __restrict__ wb0,
    const unsigned short* __restrict__ wb1,
    unsigned short* __restrict__ x0buf, unsigned short* __restrict__ x1buf,
    const float* __restrict__ hstate, const float* __restrict__ cstate,
    const float* __restrict__ wih, const float* __restrict__ whh,
    const float* __restrict__ bih, const float* __restrict__ bhh,
    float* __restrict__ h1buf, float* __restrict__ h2buf,
    unsigned* __restrict__ cflags, unsigned* __restrict__ cepoch,
    unsigned* __restrict__ lflags, unsigned* __restrict__ lepoch,
    float* __restrict__ dout) {

    __shared__ __align__(16) unsigned short xs_hi[97 * CKP];   // 51216 B
    __shared__ __align__(16) unsigned short xs_lo[97 * CKP];   // 51216 B
    __shared__ __align__(16) float part[4 * 16 * 96];          // 24576 B
    __shared__ __align__(16) float hx[EMB], hb2[EMB], ex[EMB];
    __shared__ float g1s[16], g2s[16], c1s[4], c2s[4];

    const int tid = threadIdx.x;

    if (blockIdx.x < CONV_WG) {
        const int wv = tid >> 6;
        const int ln = tid & 63;
        const int lj = ln & 15;
        const int lg = ln >> 4;
        const int bI = blockIdx.x;
        const int r0 = bI * 16;

        if (use_b16) {
            bf16x8 W0a[3][2], W1a[3][2], W0b[3][2], W1b[3][2];
            ISSUE_W_B16(0, W0a, W1a);
#pragma unroll 1
            for (int lay = 0; lay + 1 < NLAYER; lay += 2) {
                CONV_LAYER_B16(lay, W0a, W1a, W0b, W1b);
                CONV_LAYER_B16(lay + 1, W0b, W1b, W0a, W1a);
            }
            CONV_LAYER_B16(NLAYER - 1, W0a, W1a, W0b, W1b);
        } else {
            float4 Wa[3][2][4], Wb[3][2][4];
            ISSUE_W_F32(0, Wa);
#pragma unroll 1
            for (int lay = 0; lay + 1 < NLAYER; lay += 2) {
                CONV_LAYER_F32(lay, Wa, Wb);
                CONV_LAYER_F32(lay + 1, Wb, Wa);
            }
            CONV_LAYER_F32(NLAYER - 1, Wa, Wb);
        }
    } else {
        // ====== LSTM path: 97 ticks, skewed layers, fused W_ih1 ===========
        const int wg   = blockIdx.x - CONV_WG;    // 0..191
        const int l16  = tid & 15;
        const int r16  = tid >> 4;
        const int gate = r16 >> 2;
        const int jl   = r16 & 3;
        const int j0   = wg * 4;
        const int grow = gate * EMB + j0 + jl;

        float wi1r[48], wh1r[48], wi2r[48], wh2r[48];
        const float* wih1 = wih;
        const float* whh1 = whh;
        const float* wih2 = wih + (size_t)G4 * EMB;
        const float* whh2 = whh + (size_t)G4 * EMB;
#pragma unroll
        for (int i = 0; i < 48; ++i) {
            const int k = l16 + (i << 4);
            wi1r[i] = wih1[(size_t)grow * EMB + k];
            wh1r[i] = whh1[(size_t)grow * EMB + k];
            wi2r[i] = wih2[(size_t)grow * EMB + k];
            wh2r[i] = whh2[(size_t)grow * EMB + k];
        }
        const float b1 = bih[grow] + bhh[grow];
        const float b2 = bih[G4 + grow] + bhh[G4 + grow];

        if (tid < 4)      c1s[tid]     = cstate[j0 + tid];
        else if (tid < 8) c2s[tid - 4] = cstate[EMB + j0 + (tid - 4)];
        __syncthreads();

        for (int T = 0; T <= SEQ; ++T) {
            if (tid < 192) {
                if (T < SEQ) {     // emb1 staging: plain cached loads
                    const int tok = xids[T];
                    float4 v = *(const float4*)(emb1 + (size_t)tok * EMB + tid * 4);
                    *(float4*)(ex + tid * 4) = v;
                }
                ull a0, a1;
                if (T == 0) {
                    a0 = ld64g(hstate + tid * 4);
                    a1 = ld64g(hstate + tid * 4 + 2);
                } else {
                    a0 = ld64g(h1buf + (T - 1) * EMB + tid * 4);
                    a1 = ld64g(h1buf + (T - 1) * EMB + tid * 4 + 2);
                }
                *(ull*)(hx + tid * 4)     = a0;
                *(ull*)(hx + tid * 4 + 2) = a1;
                ull b0 = 0, b1v = 0;
                if (T >= 1) {
                    if (T == 1) {
                        b0  = ld64g(hstate + EMB + tid * 4);
                        b1v = ld64g(hstate + EMB + tid * 4 + 2);
                    } else {
                        b0  = ld64g(h2buf + (T - 2) * EMB + tid * 4);
                        b1v = ld64g(h2buf + (T - 2) * EMB + tid * 4 + 2);
                    }
                }
                *(ull*)(hb2 + tid * 4)     = b0;
                *(ull*)(hb2 + tid * 4 + 2) = b1v;
            }
            __syncthreads();

            if (T < SEQ) {
                float a = b1;
#pragma unroll
                for (int i = 0; i < 48; ++i)
                    a = fmaf(wi1r[i], ex[l16 + (i << 4)], a);
#pragma unroll
                for (int i = 0; i < 48; ++i)
                    a = fmaf(wh1r[i], hx[l16 + (i << 4)], a);
                a = red16(a);
                if (l16 == 0) g1s[r16] = a;
            }
            if (T >= 1) {
                float b = b2;
#pragma unroll
                for (int i = 0; i < 48; ++i)
                    b = fmaf(wi2r[i], hx[l16 + (i << 4)], b);
#pragma unroll
                for (int i = 0; i < 48; ++i)
                    b = fmaf(wh2r[i], hb2[l16 + (i << 4)], b);
                b = red16(b);
                if (l16 == 0) g2s[r16] = b;
            }
            __syncthreads();

            if (tid < 4 && T < SEQ) {
                const int j = tid;
                const float i_ = sigmoidf_(g1s[j]);
                const float f_ = sigmoidf_(g1s[4 + j]);
                const float g_ = tanhf(g1s[8 + j]);
                const float o_ = sigmoidf_(g1s[12 + j]);
                const float c  = f_ * c1s[j] + i_ * g_;
                c1s[j] = c;
                const float h = o_ * tanhf(c);
                stf32g(&h1buf[T * EMB + j0 + j], h);
                if (T == SEQ - 1) {
                    dout[1 + j0 + j]    = h;   // h[0]
                    dout[1537 + j0 + j] = c;   // c[0]
                }
            } else if (tid >= 4 && tid < 8 && T >= 1) {
                const int j = tid - 4;
                const int s = T - 1;
                const float i_ = sigmoidf_(g2s[j]);
                const float f_ = sigmoidf_(g2s[4 + j]);
                const float g_ = tanhf(g2s[8 + j]);
                const float o_ = sigmoidf_(g2s[12 + j]);
                const float c  = f_ * c2s[j] + i_ * g_;
                c2s[j] = c;
                const float h = o_ * tanhf(c);
                stf32g(&h2buf[s * EMB + j0 + j], h);
                if (s == SEQ - 1) {
                    dout[1 + EMB + j0 + j]    = h;   // h[1]
                    dout[1537 + EMB + j0 + j] = c;   // c[1]
                }
            }
            if (T < SEQ)
                relbar(lflags, lepoch, LSTM_WG, wg, (unsigned)(T + 1));
        }
    }
}

// ---------------- deterministic scalar epilogue ---------------------------
__global__ void k_final(const float* __restrict__ pred_w,
                        const float* __restrict__ pred_b,
                        const float* __restrict__ m2w,
                        const float* __restrict__ m2b,
                        const float* __restrict__ prev,
                        float* __restrict__ dout) {
    __shared__ float red[256];
    const int tid = threadIdx.x;
    float p1 = 0.f;
    for (int idx = tid; idx < 2 * EMB; idx += 256) {
        const int l = idx / EMB;
        const int j = idx - l * EMB;
        p1 += dout[1537 + idx] * pred_w[j * 2 + l];
    }
    float p2 = 0.f;
    for (int e = tid; e < EMB; e += 256)
        p2 += dout[3074 + e] * m2w[2 * e] + prev[e] * m2w[2 * e + 1];

    red[tid] = p1;
    __syncthreads();
    for (int s = 128; s > 0; s >>= 1) {
        if (tid < s) red[tid] += red[tid + s];
        __syncthreads();
    }
    if (tid == 0) dout[0] = red[0] + pred_b[0];
    __syncthreads();
    red[tid] = p2;
    __syncthreads();
    for (int s = 128; s > 0; s >>= 1) {
        if (tid < s) red[tid] += red[tid + s];
        __syncthreads();
    }
    if (tid == 0) dout[3073] = red[0] + m2b[0];
}

extern "C" void kernel_launch(void* const* d_in, const int* in_sizes, int n_in,
                              void* d_out, int out_size, void* d_ws, size_t ws_size,
                              hipStream_t stream) {
    const int*   x      = (const int*)d_in[0];
    const float* hstate = (const float*)d_in[1];
    const float* cstate = (const float*)d_in[2];
    const float* prev   = (const float*)d_in[3];
    const float* emb1   = (const float*)d_in[4];
    const float* emb2   = (const float*)d_in[5];
    const float* wih    = (const float*)d_in[6];
    const float* whh    = (const float*)d_in[7];
    const float* bih    = (const float*)d_in[8];
    const float* bhh    = (const float*)d_in[9];
    const float* predw  = (const float*)d_in[10];
    const float* predb  = (const float*)d_in[11];
    const float* convw  = (const float*)d_in[12];
    const float* convb  = (const float*)d_in[13];
    const float* m2w    = (const float*)d_in[14];
    const float* m2b    = (const float*)d_in[15];
    float* out = (float*)d_out;

    // ws layout (bytes): [0,32768) flags; then h1,h2 (f32), x0,x1 (u16),
    // then wb0, wb1 bf16 weight planes (if ws_size allows).
    char* wsb = (char*)d_ws;
    unsigned* wsw = (unsigned*)d_ws;
    unsigned* cflags = wsw;            // words [0 .. 768)
    unsigned* cepoch = wsw + 1024;     // 32 replicas
    unsigned* lflags = wsw + 2048;     // 192 x stride16
    unsigned* lepoch = wsw + 6144;     // 32 replicas
    float* h1buf = (float*)(wsb + 32768);                       // 294912 B
    float* h2buf = (float*)(wsb + 32768 + 294912);              // 294912 B
    unsigned short* x0buf = (unsigned short*)(wsb + 622592);    // 294912 B
    unsigned short* x1buf = (unsigned short*)(wsb + 917504);    // 294912 B
    unsigned short* wb0   = (unsigned short*)(wsb + 1212416);   // 112066560 B
    unsigned short* wb1   = (unsigned short*)(wsb + 113278976); // 112066560 B
    const int use_b16 = (ws_size >= WB_BYTES) ? 1 : 0;

    hipMemsetAsync(d_ws, 0, 32768, stream);
    hipMemsetAsync(d_out, 0, out_size * sizeof(float), stream);

    if (use_b16)
        k_prep<<<54720, 256, 0, stream>>>(convw, wb0, wb1);
    k_embed<<<96, 256, 0, stream>>>(x, emb2, x0buf);
    k_net<<<CONV_WG + LSTM_WG, 256, 0, stream>>>(
        use_b16, x, emb1, convw, convb, wb0, wb1, x0buf, x1buf,
        hstate, cstate, wih, whh, bih, bhh, h1buf, h2buf,
        cflags, cepoch, lflags, lepoch, out);
    k_final<<<1, 256, 0, stream>>>(predw, predb, m2w, m2b, prev, out);
}

// Round 17
// 1137.936 us; speedup vs baseline: 2.1409x; 2.1409x over previous
//
#include <hip/hip_runtime.h>
#include <math.h>

#define SEQ 96
#define EMB 768
#define G4  3072   // 4*H
#define NLAYER 95  // conv layers
#define CKP 264    // xs col pitch (bf16 elems): 256 k-chunk + 8 pad
#define CONV_WG 48
#define LSTM_WG 192
#define NREP 32      // epoch replica lines
#define XPITCH 1536  // ushorts per col in x buffers: 48 blocks x (hi16|lo16)
#define WB_BYTES 225345536ull   // ws bytes needed for bf16 weight planes path

typedef float  f32x4  __attribute__((ext_vector_type(4)));
typedef short  bf16x8 __attribute__((ext_vector_type(8)));
typedef unsigned long long ull;

union BF8 { unsigned short u[8]; bf16x8 v; };

__device__ __forceinline__ unsigned short f2bf(float f) {   // RNE fp32->bf16
    unsigned u = __float_as_uint(f);
    u += 0x7FFFu + ((u >> 16) & 1u);
    return (unsigned short)(u >> 16);
}
__device__ __forceinline__ float bf2f(unsigned short u) {
    return __uint_as_float(((unsigned)u) << 16);
}

// ---- sc1 (LLC-direct, coherent) loads/stores for cross-WG mutable data ---
__device__ __forceinline__ ull ld64g(const void* p) {
    return __hip_atomic_load((const ull*)p, __ATOMIC_RELAXED,
                             __HIP_MEMORY_SCOPE_AGENT);
}
__device__ __forceinline__ void st32g(void* p, unsigned v) {
    __hip_atomic_store((unsigned*)p, v, __ATOMIC_RELAXED,
                       __HIP_MEMORY_SCOPE_AGENT);
}
__device__ __forceinline__ void stf32g(float* p, float v) {
    __hip_atomic_store((unsigned*)p, __float_as_uint(v), __ATOMIC_RELAXED,
                       __HIP_MEMORY_SCOPE_AGENT);
}
__device__ __forceinline__ unsigned ldflag(const unsigned* p) {
    return __hip_atomic_load(p, __ATOMIC_RELAXED, __HIP_MEMORY_SCOPE_AGENT);
}
__device__ __forceinline__ void stflag(unsigned* p, unsigned v) {
    __hip_atomic_store(p, v, __ATOMIC_RELAXED, __HIP_MEMORY_SCOPE_AGENT);
}

// ------ grid barrier: sc1 flags, 32 epoch replicas, NO invalidates --------
__device__ __forceinline__ void relbar(unsigned* flags, unsigned* epoch,
                                       int nwg, int wg, unsigned target) {
    asm volatile("s_waitcnt vmcnt(0)" ::: "memory");
    __syncthreads();
    if (threadIdx.x == 0) stflag(&flags[wg * 16], target);
    if (wg == 0) {
        if ((int)threadIdx.x < nwg)
            while (ldflag(&flags[threadIdx.x * 16]) < target)
                __builtin_amdgcn_s_sleep(2);
        __syncthreads();
        if (threadIdx.x < NREP) stflag(&epoch[threadIdx.x * 16], target);
    }
    if (threadIdx.x == 0) {
        const unsigned* ep = &epoch[(wg & (NREP - 1)) * 16];
        while (ldflag(ep) < target)
            __builtin_amdgcn_s_sleep(8);
    }
    asm volatile("" ::: "memory");
    __syncthreads();
}

__device__ __forceinline__ float red16(float a) {
    a += __shfl_xor(a, 8, 16);
    a += __shfl_xor(a, 4, 16);
    a += __shfl_xor(a, 2, 16);
    a += __shfl_xor(a, 1, 16);
    return a;
}

__device__ __forceinline__ float sigmoidf_(float x) {
    return 1.0f / (1.0f + __expf(-x));
}

// ---- weight prep: fp32 interleaved (w0,w1) -> bf16 planes wb0, wb1 -------
__global__ void k_prep(const float* __restrict__ w,
                       unsigned short* __restrict__ wb0,
                       unsigned short* __restrict__ wb1) {
    const size_t p0 = ((size_t)blockIdx.x * 256 + threadIdx.x) * 4;
    const f32x4* src = (const f32x4*)(w + p0 * 2);
    f32x4 f0 = __builtin_nontemporal_load(src);
    f32x4 f1 = __builtin_nontemporal_load(src + 1);
    ushort4 a, b;
    a.x = f2bf(f0.x); b.x = f2bf(f0.y);
    a.y = f2bf(f0.z); b.y = f2bf(f0.w);
    a.z = f2bf(f1.x); b.z = f2bf(f1.y);
    a.w = f2bf(f1.z); b.w = f2bf(f1.w);
    *(ushort4*)(wb0 + p0) = a;
    *(ushort4*)(wb1 + p0) = b;
}

// ---------------- emb2 gather -> hi/lo bf16 x0 ----------------------------
__global__ void k_embed(const int* __restrict__ xids,
                        const float* __restrict__ emb2,
                        unsigned short* __restrict__ x0) {
    const int col = blockIdx.x;                 // 96 blocks
    const int tok = xids[col];
    const int tid = threadIdx.x;
    if (tid < 192) {
        float4 v = *(const float4*)(emb2 + (size_t)tok * EMB + tid * 4);
        ushort4 hv, lv;
        hv.x = f2bf(v.x); lv.x = f2bf(v.x - bf2f(hv.x));
        hv.y = f2bf(v.y); lv.y = f2bf(v.y - bf2f(hv.y));
        hv.z = f2bf(v.z); lv.z = f2bf(v.z - bf2f(hv.z));
        hv.w = f2bf(v.w); lv.w = f2bf(v.w - bf2f(hv.w));
        unsigned short* base = x0 + col * XPITCH + (tid >> 2) * 32 + (tid & 3) * 4;
        *(ushort4*)base        = hv;
        *(ushort4*)(base + 16) = lv;
    }
}

// ---- issue one layer's weight slab (8-wave split: 6 x bf16x8) ------------
#define ISSUE_W_B16(LAY, W0R, W1R) do {                                      \
    const unsigned short* w0_ = wb0 + ((size_t)(LAY) * EMB + r0 + lj) * EMB; \
    const unsigned short* w1_ = wb1 + ((size_t)(LAY) * EMB + r0 + lj) * EMB; \
    _Pragma("unroll")                                                        \
    for (int ch_ = 0; ch_ < 3; ++ch_) {                                      \
        const int k_ = ch_ * 256 + wv * 32 + lg * 8;                         \
        W0R[ch_] = *(const bf16x8*)(w0_ + k_);                               \
        W1R[ch_] = *(const bf16x8*)(w1_ + k_);                               \
    }                                                                        \
} while (0)

// ---- conv barrier tail with in-barrier prefetch (r14-proven) -------------
#define CONV_BARRIER(LAY, PREFETCH) do {                                     \
    if ((LAY) + 1 < NLAYER) {                                                \
        const unsigned tgt = (unsigned)((LAY) + 1);                          \
        asm volatile("s_waitcnt vmcnt(0)" ::: "memory");                     \
        __syncthreads();                                                     \
        if (tid == 0) stflag(&cflags[bI * 16], tgt);                         \
        PREFETCH;                                                            \
        asm volatile("" ::: "memory");                                       \
        if (bI == 0) {                                                       \
            if (tid < CONV_WG)                                               \
                while (ldflag(&cflags[tid * 16]) < tgt)                      \
                    __builtin_amdgcn_s_sleep(2);                             \
            __syncthreads();                                                 \
            if (tid < NREP) stflag(&cepoch[tid * 16], tgt);                  \
        }                                                                    \
        if (tid == 0) {                                                      \
            const unsigned* ep = &cepoch[(bI & (NREP - 1)) * 16];            \
            while (ldflag(ep) < tgt)                                         \
                __builtin_amdgcn_s_sleep(8);                                 \
        }                                                                    \
        asm volatile("" ::: "memory");                                       \
        __syncthreads();                                                     \
    }                                                                        \
} while (0)

// ---- epilogue: 8-way K-split reduce + relu + packed hi/lo sc1 store ------
#define CONV_EPILOGUE(LAY) do {                                              \
    _Pragma("unroll")                                                        \
    for (int nt = 0; nt < 6; ++nt) if (nt < nts)                             \
        *(f32x4*)&part[wv * 1536 + (nt * 16 + lj) * 16 + lg * 4] = acc[nt];  \
    __syncthreads();                                                         \
    _Pragma("unroll")                                                        \
    for (int j = 0; j < 2; ++j) {                                            \
        const int o2 = tid + j * 512;                                        \
        const int c = o2 >> 3, p = o2 & 7;                                   \
        if (c < ncols) {                                                     \
            const int i0 = p * 2;                                            \
            const int oo = c * 16 + i0;                                      \
            float s0 = conv_b[(LAY) * EMB + r0 + i0];                        \
            float s1 = conv_b[(LAY) * EMB + r0 + i0 + 1];                    \
            _Pragma("unroll")                                                \
            for (int w = 0; w < 8; ++w) {                                    \
                s0 += part[w * 1536 + oo];                                   \
                s1 += part[w * 1536 + oo + 1];                               \
            }                                                                \
            s0 = fmaxf(s0, 0.f); s1 = fmaxf(s1, 0.f);                        \
            const unsigned short h0 = f2bf(s0), h1 = f2bf(s1);               \
            const unsigned short l0 = f2bf(s0 - bf2f(h0));                   \
            const unsigned short l1 = f2bf(s1 - bf2f(h1));                   \
            unsigned short* dp = dst + c * XPITCH + bI * 32 + i0;            \
            st32g(dp,      (unsigned)h0 | ((unsigned)h1 << 16));             \
            st32g(dp + 16, (unsigned)l0 | ((unsigned)l1 << 16));             \
            if ((LAY) == NLAYER - 1 && c == 0) {                             \
                dout[3074 + r0 + i0]     = s0;                               \
                dout[3074 + r0 + i0 + 1] = s1;                               \
            }                                                                \
        }                                                                    \
    }                                                                        \
} while (0)

// ---- x-chunk restage: batched sc1 loads (512 threads, 24x8B) -> LDS ------
#define STAGE_X(CH) do {                                                     \
    ull Rst[6][4];                                                           \
    _Pragma("unroll")                                                        \
    for (int j = 0; j < 6; ++j) {                                            \
        const int u = tid + j * 512;                                         \
        const int c = u >> 5, q = u & 31;                                    \
        if (c < scols) {                                                     \
            const int k = (CH) * 256 + q * 8;                                \
            const unsigned short* sp =                                       \
                src + c * XPITCH + ((k >> 4) << 5) + (k & 15);               \
            Rst[j][0] = ld64g(sp);                                           \
            Rst[j][1] = ld64g(sp + 4);                                       \
            Rst[j][2] = ld64g(sp + 16);                                      \
            Rst[j][3] = ld64g(sp + 20);                                      \
        }                                                                    \
    }                                                                        \
    _Pragma("unroll")                                                        \
    for (int j = 0; j < 6; ++j) {                                            \
        const int u = tid + j * 512;                                         \
        const int c = u >> 5, q = u & 31;                                    \
        if (c < scols) {                                                     \
            *(ull*)(xs_hi + c * CKP + q * 8)     = Rst[j][0];                \
            *(ull*)(xs_hi + c * CKP + q * 8 + 4) = Rst[j][1];                \
            *(ull*)(xs_lo + c * CKP + q * 8)     = Rst[j][2];                \
            *(ull*)(xs_lo + c * CKP + q * 8 + 4) = Rst[j][3];                \
        }                                                                    \
    }                                                                        \
} while (0)

// ---- one chunk's MFMA work (1 Ktile per wave), bf16 weight regs ----------
#define CONV_CHUNK_B16(CH, W0c, W1c) do {                                    \
    const bf16x8 a0 = W0c[CH];                                               \
    const bf16x8 a1 = W1c[CH];                                               \
    const int klocal = wv * 32;                                              \
    _Pragma("unroll")                                                        \
    for (int nt = 0; nt < 6; ++nt) if (nt < nts) {                           \
        const int co = (nt * 16 + lj) * CKP + klocal + lg * 8;               \
        bf16x8 bh0 = *(const bf16x8*)(xs_hi + co);                           \
        bf16x8 bl0 = *(const bf16x8*)(xs_lo + co);                           \
        bf16x8 bh1 = *(const bf16x8*)(xs_hi + co + CKP);                     \
        bf16x8 bl1 = *(const bf16x8*)(xs_lo + co + CKP);                     \
        acc[nt] = __builtin_amdgcn_mfma_f32_16x16x32_bf16(                   \
                      a0, bh0, acc[nt], 0, 0, 0);                            \
        acc[nt] = __builtin_amdgcn_mfma_f32_16x16x32_bf16(                   \
                      a0, bl0, acc[nt], 0, 0, 0);                            \
        acc[nt] = __builtin_amdgcn_mfma_f32_16x16x32_bf16(                   \
                      a1, bh1, acc[nt], 0, 0, 0);                            \
        acc[nt] = __builtin_amdgcn_mfma_f32_16x16x32_bf16(                   \
                      a1, bl1, acc[nt], 0, 0, 0);                            \
    }                                                                        \
} while (0)

// ---- full conv layer, bf16 weight planes ---------------------------------
#define CONV_LAYER_B16(LAY, W0c, W1c, W0n, W1n) do {                         \
    const int ncols = NLAYER - (LAY);                                        \
    const int scols = (ncols + 1 < 96) ? ncols + 1 : 96;                     \
    const int nts   = (ncols + 15) >> 4;                                     \
    const unsigned short* src = ((LAY) & 1) ? x1buf : x0buf;                 \
    unsigned short*       dst = ((LAY) & 1) ? x0buf : x1buf;                 \
    f32x4 acc[6];                                                            \
    _Pragma("unroll")                                                        \
    for (int n = 0; n < 6; ++n) acc[n] = (f32x4)0.f;                         \
    _Pragma("unroll")                                                        \
    for (int ch = 0; ch < 3; ++ch) {                                         \
        STAGE_X(ch);                                                         \
        __syncthreads();                                                     \
        CONV_CHUNK_B16(ch, W0c, W1c);                                        \
        __syncthreads();                                                     \
    }                                                                        \
    CONV_EPILOGUE(LAY);                                                      \
    CONV_BARRIER(LAY, ISSUE_W_B16((LAY) + 1, W0n, W1n));                     \
} while (0)

// ---- fp32 fallback: weight slab in float4 regs (8-wave split) ------------
#define ISSUE_W_F32(LAY, WREG) do {                                          \
    const float* wsl_ = conv_w + (size_t)(LAY) * (EMB * EMB * 2)             \
                               + (size_t)(r0 + lj) * (EMB * 2);              \
    _Pragma("unroll")                                                        \
    for (int ch_ = 0; ch_ < 3; ++ch_) {                                      \
        const int K0_ = ch_ * 256 + wv * 32;                                 \
        const float4* ap_ =                                                  \
            (const float4*)(wsl_ + (size_t)(K0_ + lg * 8) * 2);              \
        _Pragma("unroll")                                                    \
        for (int j_ = 0; j_ < 4; ++j_) WREG[ch_][j_] = ap_[j_];              \
    }                                                                        \
} while (0)

#define CONV_LAYER_F32(LAY, Wc, Wn) do {                                     \
    const int ncols = NLAYER - (LAY);                                        \
    const int scols = (ncols + 1 < 96) ? ncols + 1 : 96;                     \
    const int nts   = (ncols + 15) >> 4;                                     \
    const unsigned short* src = ((LAY) & 1) ? x1buf : x0buf;                 \
    unsigned short*       dst = ((LAY) & 1) ? x0buf : x1buf;                 \
    f32x4 acc[6];                                                            \
    _Pragma("unroll")                                                        \
    for (int n = 0; n < 6; ++n) acc[n] = (f32x4)0.f;                         \
    _Pragma("unroll")                                                        \
    for (int ch = 0; ch < 3; ++ch) {                                         \
        STAGE_X(ch);                                                         \
        __syncthreads();                                                     \
        {                                                                    \
            BF8 a0h, a0l, a1h, a1l;                                          \
            _Pragma("unroll")                                                \
            for (int d = 0; d < 8; ++d) {                                    \
                const float4 f = Wc[ch][d >> 1];                             \
                const float w0 = (d & 1) ? f.z : f.x;                        \
                const float w1 = (d & 1) ? f.w : f.y;                        \
                const unsigned short h0 = f2bf(w0);                          \
                const unsigned short h1 = f2bf(w1);                          \
                a0h.u[d] = h0; a0l.u[d] = f2bf(w0 - bf2f(h0));               \
                a1h.u[d] = h1; a1l.u[d] = f2bf(w1 - bf2f(h1));               \
            }                                                                \
            const int klocal = wv * 32;                                      \
            _Pragma("unroll")                                                \
            for (int nt = 0; nt < 6; ++nt) if (nt < nts) {                   \
                const int co = (nt * 16 + lj) * CKP + klocal + lg * 8;       \
                bf16x8 bh0 = *(const bf16x8*)(xs_hi + co);                   \
                bf16x8 bl0 = *(const bf16x8*)(xs_lo + co);                   \
                bf16x8 bh1 = *(const bf16x8*)(xs_hi + co + CKP);             \
                bf16x8 bl1 = *(const bf16x8*)(xs_lo + co + CKP);             \
                acc[nt] = __builtin_amdgcn_mfma_f32_16x16x32_bf16(           \
                              a0h.v, bh0, acc[nt], 0, 0, 0);                 \
                acc[nt] = __builtin_amdgcn_mfma_f32_16x16x32_bf16(           \
                              a0h.v, bl0, acc[nt], 0, 0, 0);                 \
                acc[nt] = __builtin_amdgcn_mfma_f32_16x16x32_bf16(           \
                              a0l.v, bh0, acc[nt], 0, 0, 0);                 \
                acc[nt] = __builtin_amdgcn_mfma_f32_16x16x32_bf16(           \
                              a1h.v, bh1, acc[nt], 0, 0, 0);                 \
                acc[nt] = __builtin_amdgcn_mfma_f32_16x16x32_bf16(           \
                              a1h.v, bl1, acc[nt], 0, 0, 0);                 \
                acc[nt] = __builtin_amdgcn_mfma_f32_16x16x32_bf16(           \
                              a1l.v, bh1, acc[nt], 0, 0, 0);                 \
            }                                                                \
        }                                                                    \
        __syncthreads();                                                     \
    }                                                                        \
    CONV_EPILOGUE(LAY);                                                      \
    CONV_BARRIER(LAY, ISSUE_W_F32((LAY) + 1, Wn));                           \
} while (0)

// ------- fused persistent kernel: 48 conv WGs (8 waves) + 192 LSTM WGs ----
__global__ __launch_bounds__(512, 1) void k_net(
    const int use_b16,
    const int* __restrict__ xids, const float* __restrict__ emb1,
    const float* __restrict__ conv_w, const float* __restrict__ conv_b,
    const unsigned short* __restrict__ wb0,
    const unsigned short* __restrict__ wb1,
    unsigned short* __restrict__ x0buf, unsigned short* __restrict__ x1buf,
    const float* __restrict__ hstate, const float* __restrict__ cstate,
    const float* __restrict__ wih, const float* __restrict__ whh,
    const float* __restrict__ bih, const float* __restrict__ bhh,
    float* __restrict__ h1buf, float* __restrict__ h2buf,
    unsigned* __restrict__ cflags, unsigned* __restrict__ cepoch,
    unsigned* __restrict__ lflags, unsigned* __restrict__ lepoch,
    float* __restrict__ dout) {

    __shared__ __align__(16) unsigned short xs_hi[97 * CKP];   // 51216 B
    __shared__ __align__(16) unsigned short xs_lo[97 * CKP];   // 51216 B
    __shared__ __align__(16) float hx[EMB], hb2[EMB], ex[EMB];
    __shared__ float g1s[16], g2s[16], c1s[4], c2s[4];
    float* part = (float*)xs_hi;   // 8*1536 f32 = 49152 B, aliased (safe:
                                   // written only after last chunk consumed)

    const int tid = threadIdx.x;

    if (blockIdx.x < CONV_WG) {
        const int wv = tid >> 6;           // wave 0..7 (K-split)
        const int ln = tid & 63;
        const int lj = ln & 15;
        const int lg = ln >> 4;
        const int bI = blockIdx.x;
        const int r0 = bI * 16;

        if (use_b16) {
            bf16x8 W0a[3], W1a[3], W0b[3], W1b[3];
            ISSUE_W_B16(0, W0a, W1a);
#pragma unroll 1
            for (int lay = 0; lay + 1 < NLAYER; lay += 2) {
                CONV_LAYER_B16(lay, W0a, W1a, W0b, W1b);
                CONV_LAYER_B16(lay + 1, W0b, W1b, W0a, W1a);
            }
            CONV_LAYER_B16(NLAYER - 1, W0a, W1a, W0b, W1b);
        } else {
            float4 Wa[3][4], Wb[3][4];
            ISSUE_W_F32(0, Wa);
#pragma unroll 1
            for (int lay = 0; lay + 1 < NLAYER; lay += 2) {
                CONV_LAYER_F32(lay, Wa, Wb);
                CONV_LAYER_F32(lay + 1, Wb, Wa);
            }
            CONV_LAYER_F32(NLAYER - 1, Wa, Wb);
        }
    } else {
        // ====== LSTM path: 97 ticks, work on tid<256, extra waves idle ====
        const int wg   = blockIdx.x - CONV_WG;    // 0..191
        const bool act = tid < 256;
        const int l16  = tid & 15;
        const int r16  = (tid & 255) >> 4;
        const int gate = r16 >> 2;
        const int jl   = r16 & 3;
        const int j0   = wg * 4;
        const int grow = gate * EMB + j0 + jl;

        float wi1r[48], wh1r[48], wi2r[48], wh2r[48];
        float b1 = 0.f, b2 = 0.f;
        if (act) {
            const float* wih1 = wih;
            const float* whh1 = whh;
            const float* wih2 = wih + (size_t)G4 * EMB;
            const float* whh2 = whh + (size_t)G4 * EMB;
#pragma unroll
            for (int i = 0; i < 48; ++i) {
                const int k = l16 + (i << 4);
                wi1r[i] = wih1[(size_t)grow * EMB + k];
                wh1r[i] = whh1[(size_t)grow * EMB + k];
                wi2r[i] = wih2[(size_t)grow * EMB + k];
                wh2r[i] = whh2[(size_t)grow * EMB + k];
            }
            b1 = bih[grow] + bhh[grow];
            b2 = bih[G4 + grow] + bhh[G4 + grow];
        }

        if (tid < 4)      c1s[tid]     = cstate[j0 + tid];
        else if (tid < 8) c2s[tid - 4] = cstate[EMB + j0 + (tid - 4)];
        __syncthreads();

        for (int T = 0; T <= SEQ; ++T) {
            if (tid < 192) {
                if (T < SEQ) {     // emb1 staging: plain cached loads
                    const int tok = xids[T];
                    float4 v = *(const float4*)(emb1 + (size_t)tok * EMB + tid * 4);
                    *(float4*)(ex + tid * 4) = v;
                }
                ull a0, a1;
                if (T == 0) {
                    a0 = ld64g(hstate + tid * 4);
                    a1 = ld64g(hstate + tid * 4 + 2);
                } else {
                    a0 = ld64g(h1buf + (T - 1) * EMB + tid * 4);
                    a1 = ld64g(h1buf + (T - 1) * EMB + tid * 4 + 2);
                }
                *(ull*)(hx + tid * 4)     = a0;
                *(ull*)(hx + tid * 4 + 2) = a1;
                ull b0 = 0, b1v = 0;
                if (T >= 1) {
                    if (T == 1) {
                        b0  = ld64g(hstate + EMB + tid * 4);
                        b1v = ld64g(hstate + EMB + tid * 4 + 2);
                    } else {
                        b0  = ld64g(h2buf + (T - 2) * EMB + tid * 4);
                        b1v = ld64g(h2buf + (T - 2) * EMB + tid * 4 + 2);
                    }
                }
                *(ull*)(hb2 + tid * 4)     = b0;
                *(ull*)(hb2 + tid * 4 + 2) = b1v;
            }
            __syncthreads();

            if (act && T < SEQ) {
                float a = b1;
#pragma unroll
                for (int i = 0; i < 48; ++i)
                    a = fmaf(wi1r[i], ex[l16 + (i << 4)], a);
#pragma unroll
                for (int i = 0; i < 48; ++i)
                    a = fmaf(wh1r[i], hx[l16 + (i << 4)], a);
                a = red16(a);
                if (l16 == 0) g1s[r16] = a;
            }
            if (act && T >= 1) {
                float b = b2;
#pragma unroll
                for (int i = 0; i < 48; ++i)
                    b = fmaf(wi2r[i], hx[l16 + (i << 4)], b);
#pragma unroll
                for (int i = 0; i < 48; ++i)
                    b = fmaf(wh2r[i], hb2[l16 + (i << 4)], b);
                b = red16(b);
                if (l16 == 0) g2s[r16] = b;
            }
            __syncthreads();

            if (tid < 4 && T < SEQ) {
                const int j = tid;
                const float i_ = sigmoidf_(g1s[j]);
                const float f_ = sigmoidf_(g1s[4 + j]);
                const float g_ = tanhf(g1s[8 + j]);
                const float o_ = sigmoidf_(g1s[12 + j]);
                const float c  = f_ * c1s[j] + i_ * g_;
                c1s[j] = c;
                const float h = o_ * tanhf(c);
                stf32g(&h1buf[T * EMB + j0 + j], h);
                if (T == SEQ - 1) {
                    dout[1 + j0 + j]    = h;   // h[0]
                    dout[1537 + j0 + j] = c;   // c[0]
                }
            } else if (tid >= 4 && tid < 8 && T >= 1) {
                const int j = tid - 4;
                const int s = T - 1;
                const float i_ = sigmoidf_(g2s[j]);
                const float f_ = sigmoidf_(g2s[4 + j]);
                const float g_ = tanhf(g2s[8 + j]);
                const float o_ = sigmoidf_(g2s[12 + j]);
                const float c  = f_ * c2s[j] + i_ * g_;
                c2s[j] = c;
                const float h = o_ * tanhf(c);
                stf32g(&h2buf[s * EMB + j0 + j], h);
                if (s == SEQ - 1) {
                    dout[1 + EMB + j0 + j]    = h;   // h[1]
                    dout[1537 + EMB + j0 + j] = c;   // c[1]
                }
            }
            if (T < SEQ)
                relbar(lflags, lepoch, LSTM_WG, wg, (unsigned)(T + 1));
        }
    }
}

// ---------------- deterministic scalar epilogue ---------------------------
__global__ void k_final(const float* __restrict__ pred_w,
                        const float* __restrict__ pred_b,
                        const float* __restrict__ m2w,
                        const float* __restrict__ m2b,
                        const float* __restrict__ prev,
                        float* __restrict__ dout) {
    __shared__ float red[256];
    const int tid = threadIdx.x;
    float p1 = 0.f;
    for (int idx = tid; idx < 2 * EMB; idx += 256) {
        const int l = idx / EMB;
        const int j = idx - l * EMB;
        p1 += dout[1537 + idx] * pred_w[j * 2 + l];
    }
    float p2 = 0.f;
    for (int e = tid; e < EMB; e += 256)
        p2 += dout[3074 + e] * m2w[2 * e] + prev[e] * m2w[2 * e + 1];

    red[tid] = p1;
    __syncthreads();
    for (int s = 128; s > 0; s >>= 1) {
        if (tid < s) red[tid] += red[tid + s];
        __syncthreads();
    }
    if (tid == 0) dout[0] = red[0] + pred_b[0];
    __syncthreads();
    red[tid] = p2;
    __syncthreads();
    for (int s = 128; s > 0; s >>= 1) {
        if (tid < s) red[tid] += red[tid + s];
        __syncthreads();
    }
    if (tid == 0) dout[3073] = red[0] + m2b[0];
}

extern "C" void kernel_launch(void* const* d_in, const int* in_sizes, int n_in,
                              void* d_out, int out_size, void* d_ws, size_t ws_size,
                              hipStream_t stream) {
    const int*   x      = (const int*)d_in[0];
    const float* hstate = (const float*)d_in[1];
    const float* cstate = (const float*)d_in[2];
    const float* prev   = (const float*)d_in[3];
    const float* emb1   = (const float*)d_in[4];
    const float* emb2   = (const float*)d_in[5];
    const float* wih    = (const float*)d_in[6];
    const float* whh    = (const float*)d_in[7];
    const float* bih    = (const float*)d_in[8];
    const float* bhh    = (const float*)d_in[9];
    const float* predw  = (const float*)d_in[10];
    const float* predb  = (const float*)d_in[11];
    const float* convw  = (const float*)d_in[12];
    const float* convb  = (const float*)d_in[13];
    const float* m2w    = (const float*)d_in[14];
    const float* m2b    = (const float*)d_in[15];
    float* out = (float*)d_out;

    // ws layout (bytes): [0,32768) flags; then h1,h2 (f32), x0,x1 (u16),
    // then wb0, wb1 bf16 weight planes (if ws_size allows).
    char* wsb = (char*)d_ws;
    unsigned* wsw = (unsigned*)d_ws;
    unsigned* cflags = wsw;            // words [0 .. 768)
    unsigned* cepoch = wsw + 1024;     // 32 replicas
    unsigned* lflags = wsw + 2048;     // 192 x stride16
    unsigned* lepoch = wsw + 6144;     // 32 replicas
    float* h1buf = (float*)(wsb + 32768);                       // 294912 B
    float* h2buf = (float*)(wsb + 32768 + 294912);              // 294912 B
    unsigned short* x0buf = (unsigned short*)(wsb + 622592);    // 294912 B
    unsigned short* x1buf = (unsigned short*)(wsb + 917504);    // 294912 B
    unsigned short* wb0   = (unsigned short*)(wsb + 1212416);   // 112066560 B
    unsigned short* wb1   = (unsigned short*)(wsb + 113278976); // 112066560 B
    const int use_b16 = (ws_size >= WB_BYTES) ? 1 : 0;

    hipMemsetAsync(d_ws, 0, 32768, stream);
    hipMemsetAsync(d_out, 0, out_size * sizeof(float), stream);

    if (use_b16)
        k_prep<<<54720, 256, 0, stream>>>(convw, wb0, wb1);
    k_embed<<<96, 256, 0, stream>>>(x, emb2, x0buf);
    k_net<<<CONV_WG + LSTM_WG, 512, 0, stream>>>(
        use_b16, x, emb1, convw, convb, wb0, wb1, x0buf, x1buf,
        hstate, cstate, wih, whh, bih, bhh, h1buf, h2buf,
        cflags, cepoch, lflags, lepoch, out);
    k_final<<<1, 256, 0, stream>>>(predw, predb, m2w, m2b, prev, out);
}

// Round 18
// 950.746 us; speedup vs baseline: 2.5624x; 1.1969x over previous
//
#include <hip/hip_runtime.h>
#include <math.h>

#define SEQ 96
#define EMB 768
#define G4  3072   // 4*H
#define NLAYER 95  // conv layers
#define CKP 264    // xs col pitch (bf16 elems): 256 k-chunk + 8 pad
#define CONV_WG 48
#define LSTM_WG 192
#define NREP 32      // epoch replica lines
#define XPITCH 1536  // ushorts per col in x buffers: 48 blocks x (hi16|lo16)
#define WB_BYTES 225345536ull   // ws bytes needed for bf16 weight planes path

typedef float  f32x4  __attribute__((ext_vector_type(4)));
typedef short  bf16x8 __attribute__((ext_vector_type(8)));
typedef unsigned long long ull;

union BF8 { unsigned short u[8]; bf16x8 v; };

__device__ __forceinline__ unsigned short f2bf(float f) {   // RNE fp32->bf16
    unsigned u = __float_as_uint(f);
    u += 0x7FFFu + ((u >> 16) & 1u);
    return (unsigned short)(u >> 16);
}
__device__ __forceinline__ float bf2f(unsigned short u) {
    return __uint_as_float(((unsigned)u) << 16);
}

// ---- sc1 stores for cross-WG mutable data; consumers use plain loads +
// ---- buffer_inv (conv) or sc1 loads (LSTM).
__device__ __forceinline__ ull ld64g(const void* p) {
    return __hip_atomic_load((const ull*)p, __ATOMIC_RELAXED,
                             __HIP_MEMORY_SCOPE_AGENT);
}
__device__ __forceinline__ void st32g(void* p, unsigned v) {
    __hip_atomic_store((unsigned*)p, v, __ATOMIC_RELAXED,
                       __HIP_MEMORY_SCOPE_AGENT);
}
__device__ __forceinline__ void stf32g(float* p, float v) {
    __hip_atomic_store((unsigned*)p, __float_as_uint(v), __ATOMIC_RELAXED,
                       __HIP_MEMORY_SCOPE_AGENT);
}
__device__ __forceinline__ unsigned ldflag(const unsigned* p) {
    return __hip_atomic_load(p, __ATOMIC_RELAXED, __HIP_MEMORY_SCOPE_AGENT);
}
__device__ __forceinline__ unsigned ldflag_acq(const unsigned* p) {
    // acquire: s_waitcnt + buffer_inv (L1/L2 invalidate, no writeback)
    return __hip_atomic_load(p, __ATOMIC_ACQUIRE, __HIP_MEMORY_SCOPE_AGENT);
}
__device__ __forceinline__ void stflag(unsigned* p, unsigned v) {
    __hip_atomic_store(p, v, __ATOMIC_RELAXED, __HIP_MEMORY_SCOPE_AGENT);
}

// ------ LSTM grid barrier: sc1 flags, 32 epoch replicas, no invalidates ---
__device__ __forceinline__ void relbar(unsigned* flags, unsigned* epoch,
                                       int nwg, int wg, unsigned target) {
    asm volatile("s_waitcnt vmcnt(0)" ::: "memory");
    __syncthreads();
    if (threadIdx.x == 0) stflag(&flags[wg * 16], target);
    if (wg == 0) {
        if ((int)threadIdx.x < nwg)
            while (ldflag(&flags[threadIdx.x * 16]) < target)
                __builtin_amdgcn_s_sleep(2);
        __syncthreads();
        if (threadIdx.x < NREP) stflag(&epoch[threadIdx.x * 16], target);
    }
    if (threadIdx.x == 0) {
        const unsigned* ep = &epoch[(wg & (NREP - 1)) * 16];
        while (ldflag(ep) < target)
            __builtin_amdgcn_s_sleep(8);
    }
    asm volatile("" ::: "memory");
    __syncthreads();
}

__device__ __forceinline__ float red16(float a) {
    a += __shfl_xor(a, 8, 16);
    a += __shfl_xor(a, 4, 16);
    a += __shfl_xor(a, 2, 16);
    a += __shfl_xor(a, 1, 16);
    return a;
}

__device__ __forceinline__ float sigmoidf_(float x) {
    return 1.0f / (1.0f + __expf(-x));
}

// ---- weight prep: fp32 interleaved (w0,w1) -> bf16 planes wb0, wb1 -------
__global__ void k_prep(const float* __restrict__ w,
                       unsigned short* __restrict__ wb0,
                       unsigned short* __restrict__ wb1) {
    const size_t p0 = ((size_t)blockIdx.x * 256 + threadIdx.x) * 4;
    const f32x4* src = (const f32x4*)(w + p0 * 2);
    f32x4 f0 = __builtin_nontemporal_load(src);
    f32x4 f1 = __builtin_nontemporal_load(src + 1);
    ushort4 a, b;
    a.x = f2bf(f0.x); b.x = f2bf(f0.y);
    a.y = f2bf(f0.z); b.y = f2bf(f0.w);
    a.z = f2bf(f1.x); b.z = f2bf(f1.y);
    a.w = f2bf(f1.z); b.w = f2bf(f1.w);
    *(ushort4*)(wb0 + p0) = a;
    *(ushort4*)(wb1 + p0) = b;
}

// ---------------- emb2 gather -> hi/lo bf16 x0 ----------------------------
__global__ void k_embed(const int* __restrict__ xids,
                        const float* __restrict__ emb2,
                        unsigned short* __restrict__ x0) {
    const int col = blockIdx.x;                 // 96 blocks
    const int tok = xids[col];
    const int tid = threadIdx.x;
    if (tid < 192) {
        float4 v = *(const float4*)(emb2 + (size_t)tok * EMB + tid * 4);
        ushort4 hv, lv;
        hv.x = f2bf(v.x); lv.x = f2bf(v.x - bf2f(hv.x));
        hv.y = f2bf(v.y); lv.y = f2bf(v.y - bf2f(hv.y));
        hv.z = f2bf(v.z); lv.z = f2bf(v.z - bf2f(hv.z));
        hv.w = f2bf(v.w); lv.w = f2bf(v.w - bf2f(hv.w));
        unsigned short* base = x0 + col * XPITCH + (tid >> 2) * 32 + (tid & 3) * 4;
        *(ushort4*)base        = hv;
        *(ushort4*)(base + 16) = lv;
    }
}

// ---- issue one layer's weight slab (8-wave split: 6 x bf16x8) ------------
#define ISSUE_W_B16(LAY, W0R, W1R) do {                                      \
    const unsigned short* w0_ = wb0 + ((size_t)(LAY) * EMB + r0 + lj) * EMB; \
    const unsigned short* w1_ = wb1 + ((size_t)(LAY) * EMB + r0 + lj) * EMB; \
    _Pragma("unroll")                                                        \
    for (int ch_ = 0; ch_ < 3; ++ch_) {                                      \
        const int k_ = ch_ * 256 + wv * 32 + lg * 8;                         \
        W0R[ch_] = *(const bf16x8*)(w0_ + k_);                               \
        W1R[ch_] = *(const bf16x8*)(w1_ + k_);                               \
    }                                                                        \
} while (0)

// ---- conv barrier: in-barrier prefetch + consumer-side cache inv ---------
#define CONV_BARRIER(LAY, PREFETCH) do {                                     \
    if ((LAY) + 1 < NLAYER) {                                                \
        const unsigned tgt = (unsigned)((LAY) + 1);                          \
        asm volatile("s_waitcnt vmcnt(0)" ::: "memory");                     \
        __syncthreads();                                                     \
        if (tid == 0) stflag(&cflags[bI * 16], tgt);                         \
        PREFETCH;                                                            \
        asm volatile("" ::: "memory");                                       \
        if (bI == 0) {                                                       \
            if (tid < CONV_WG)                                               \
                while (ldflag(&cflags[tid * 16]) < tgt)                      \
                    __builtin_amdgcn_s_sleep(2);                             \
            __syncthreads();                                                 \
            if (tid < NREP) stflag(&cepoch[tid * 16], tgt);                  \
        }                                                                    \
        if (tid == 0) {                                                      \
            const unsigned* ep = &cepoch[(bI & (NREP - 1)) * 16];            \
            while (ldflag(ep) < tgt)                                         \
                __builtin_amdgcn_s_sleep(8);                                 \
            (void)ldflag_acq(ep);      /* inv L1/L2: fresh x reads */        \
        }                                                                    \
        asm volatile("" ::: "memory");                                       \
        __syncthreads();                                                     \
    }                                                                        \
} while (0)

// ---- epilogue: 8-way K-split reduce + relu + packed hi/lo sc1 store ------
#define CONV_EPILOGUE(LAY) do {                                              \
    _Pragma("unroll")                                                        \
    for (int nt = 0; nt < 6; ++nt) if (nt < nts)                             \
        *(f32x4*)&part[wv * 1536 + (nt * 16 + lj) * 16 + lg * 4] = acc[nt];  \
    __syncthreads();                                                         \
    _Pragma("unroll")                                                        \
    for (int j = 0; j < 2; ++j) {                                            \
        const int o2 = tid + j * 512;                                        \
        const int c = o2 >> 3, p = o2 & 7;                                   \
        if (c < ncols) {                                                     \
            const int i0 = p * 2;                                            \
            const int oo = c * 16 + i0;                                      \
            float s0 = conv_b[(LAY) * EMB + r0 + i0];                        \
            float s1 = conv_b[(LAY) * EMB + r0 + i0 + 1];                    \
            _Pragma("unroll")                                                \
            for (int w = 0; w < 8; ++w) {                                    \
                s0 += part[w * 1536 + oo];                                   \
                s1 += part[w * 1536 + oo + 1];                               \
            }                                                                \
            s0 = fmaxf(s0, 0.f); s1 = fmaxf(s1, 0.f);                        \
            const unsigned short h0 = f2bf(s0), h1 = f2bf(s1);               \
            const unsigned short l0 = f2bf(s0 - bf2f(h0));                   \
            const unsigned short l1 = f2bf(s1 - bf2f(h1));                   \
            unsigned short* dp = dst + c * XPITCH + bI * 32 + i0;            \
            st32g(dp,      (unsigned)h0 | ((unsigned)h1 << 16));             \
            st32g(dp + 16, (unsigned)l0 | ((unsigned)l1 << 16));             \
            if ((LAY) == NLAYER - 1 && c == 0) {                             \
                dout[3074 + r0 + i0]     = s0;                               \
                dout[3074 + r0 + i0 + 1] = s1;                               \
            }                                                                \
        }                                                                    \
    }                                                                        \
} while (0)

// ---- x-chunk restage: plain COALESCED 16B loads (inv-protected) -> LDS ---
#define STAGE_X(CH) do {                                                     \
    _Pragma("unroll")                                                        \
    for (int j = 0; j < 6; ++j) {                                            \
        const int u = tid + j * 512;                                         \
        const int c = u >> 5, q = u & 31;                                    \
        if (c < scols) {                                                     \
            const int k = (CH) * 256 + q * 8;                                \
            const unsigned short* sp =                                       \
                src + c * XPITCH + ((k >> 4) << 5) + (k & 15);               \
            bf16x8 vh = *(const bf16x8*)sp;          /* dwordx4 */           \
            bf16x8 vl = *(const bf16x8*)(sp + 16);   /* dwordx4 */           \
            *(bf16x8*)(xs_hi + c * CKP + q * 8) = vh;                        \
            *(bf16x8*)(xs_lo + c * CKP + q * 8) = vl;                        \
        }                                                                    \
    }                                                                        \
} while (0)

// ---- one chunk's MFMA work (1 Ktile per wave), bf16 weight regs ----------
#define CONV_CHUNK_B16(CH, W0c, W1c) do {                                    \
    const bf16x8 a0 = W0c[CH];                                               \
    const bf16x8 a1 = W1c[CH];                                               \
    const int klocal = wv * 32;                                              \
    _Pragma("unroll")                                                        \
    for (int nt = 0; nt < 6; ++nt) if (nt < nts) {                           \
        const int co = (nt * 16 + lj) * CKP + klocal + lg * 8;               \
        bf16x8 bh0 = *(const bf16x8*)(xs_hi + co);                           \
        bf16x8 bl0 = *(const bf16x8*)(xs_lo + co);                           \
        bf16x8 bh1 = *(const bf16x8*)(xs_hi + co + CKP);                     \
        bf16x8 bl1 = *(const bf16x8*)(xs_lo + co + CKP);                     \
        acc[nt] = __builtin_amdgcn_mfma_f32_16x16x32_bf16(                   \
                      a0, bh0, acc[nt], 0, 0, 0);                            \
        acc[nt] = __builtin_amdgcn_mfma_f32_16x16x32_bf16(                   \
                      a0, bl0, acc[nt], 0, 0, 0);                            \
        acc[nt] = __builtin_amdgcn_mfma_f32_16x16x32_bf16(                   \
                      a1, bh1, acc[nt], 0, 0, 0);                            \
        acc[nt] = __builtin_amdgcn_mfma_f32_16x16x32_bf16(                   \
                      a1, bl1, acc[nt], 0, 0, 0);                            \
    }                                                                        \
} while (0)

// ---- full conv layer, bf16 weight planes ---------------------------------
#define CONV_LAYER_B16(LAY, W0c, W1c, W0n, W1n) do {                         \
    const int ncols = NLAYER - (LAY);                                        \
    const int scols = (ncols + 1 < 96) ? ncols + 1 : 96;                     \
    const int nts   = (ncols + 15) >> 4;                                     \
    const unsigned short* src = ((LAY) & 1) ? x1buf : x0buf;                 \
    unsigned short*       dst = ((LAY) & 1) ? x0buf : x1buf;                 \
    f32x4 acc[6];                                                            \
    _Pragma("unroll")                                                        \
    for (int n = 0; n < 6; ++n) acc[n] = (f32x4)0.f;                         \
    _Pragma("unroll")                                                        \
    for (int ch = 0; ch < 3; ++ch) {                                         \
        STAGE_X(ch);                                                         \
        __syncthreads();                                                     \
        CONV_CHUNK_B16(ch, W0c, W1c);                                        \
        __syncthreads();                                                     \
    }                                                                        \
    CONV_EPILOGUE(LAY);                                                      \
    CONV_BARRIER(LAY, ISSUE_W_B16((LAY) + 1, W0n, W1n));                     \
} while (0)

// ---- fp32 fallback: weight slab in float4 regs (8-wave split) ------------
#define ISSUE_W_F32(LAY, WREG) do {                                          \
    const float* wsl_ = conv_w + (size_t)(LAY) * (EMB * EMB * 2)             \
                               + (size_t)(r0 + lj) * (EMB * 2);              \
    _Pragma("unroll")                                                        \
    for (int ch_ = 0; ch_ < 3; ++ch_) {                                      \
        const int K0_ = ch_ * 256 + wv * 32;                                 \
        const float4* ap_ =                                                  \
            (const float4*)(wsl_ + (size_t)(K0_ + lg * 8) * 2);              \
        _Pragma("unroll")                                                    \
        for (int j_ = 0; j_ < 4; ++j_) WREG[ch_][j_] = ap_[j_];              \
    }                                                                        \
} while (0)

#define CONV_LAYER_F32(LAY, Wc, Wn) do {                                     \
    const int ncols = NLAYER - (LAY);                                        \
    const int scols = (ncols + 1 < 96) ? ncols + 1 : 96;                     \
    const int nts   = (ncols + 15) >> 4;                                     \
    const unsigned short* src = ((LAY) & 1) ? x1buf : x0buf;                 \
    unsigned short*       dst = ((LAY) & 1) ? x0buf : x1buf;                 \
    f32x4 acc[6];                                                            \
    _Pragma("unroll")                                                        \
    for (int n = 0; n < 6; ++n) acc[n] = (f32x4)0.f;                         \
    _Pragma("unroll")                                                        \
    for (int ch = 0; ch < 3; ++ch) {                                         \
        STAGE_X(ch);                                                         \
        __syncthreads();                                                     \
        {                                                                    \
            BF8 a0h, a0l, a1h, a1l;                                          \
            _Pragma("unroll")                                                \
            for (int d = 0; d < 8; ++d) {                                    \
                const float4 f = Wc[ch][d >> 1];                             \
                const float w0 = (d & 1) ? f.z : f.x;                        \
                const float w1 = (d & 1) ? f.w : f.y;                        \
                const unsigned short h0 = f2bf(w0);                          \
                const unsigned short h1 = f2bf(w1);                          \
                a0h.u[d] = h0; a0l.u[d] = f2bf(w0 - bf2f(h0));               \
                a1h.u[d] = h1; a1l.u[d] = f2bf(w1 - bf2f(h1));               \
            }                                                                \
            const int klocal = wv * 32;                                      \
            _Pragma("unroll")                                                \
            for (int nt = 0; nt < 6; ++nt) if (nt < nts) {                   \
                const int co = (nt * 16 + lj) * CKP + klocal + lg * 8;       \
                bf16x8 bh0 = *(const bf16x8*)(xs_hi + co);                   \
                bf16x8 bl0 = *(const bf16x8*)(xs_lo + co);                   \
                bf16x8 bh1 = *(const bf16x8*)(xs_hi + co + CKP);             \
                bf16x8 bl1 = *(const bf16x8*)(xs_lo + co + CKP);             \
                acc[nt] = __builtin_amdgcn_mfma_f32_16x16x32_bf16(           \
                              a0h.v, bh0, acc[nt], 0, 0, 0);                 \
                acc[nt] = __builtin_amdgcn_mfma_f32_16x16x32_bf16(           \
                              a0h.v, bl0, acc[nt], 0, 0, 0);                 \
                acc[nt] = __builtin_amdgcn_mfma_f32_16x16x32_bf16(           \
                              a0l.v, bh0, acc[nt], 0, 0, 0);                 \
                acc[nt] = __builtin_amdgcn_mfma_f32_16x16x32_bf16(           \
                              a1h.v, bh1, acc[nt], 0, 0, 0);                 \
                acc[nt] = __builtin_amdgcn_mfma_f32_16x16x32_bf16(           \
                              a1h.v, bl1, acc[nt], 0, 0, 0);                 \
                acc[nt] = __builtin_amdgcn_mfma_f32_16x16x32_bf16(           \
                              a1l.v, bh1, acc[nt], 0, 0, 0);                 \
            }                                                                \
        }                                                                    \
        __syncthreads();                                                     \
    }                                                                        \
    CONV_EPILOGUE(LAY);                                                      \
    CONV_BARRIER(LAY, ISSUE_W_F32((LAY) + 1, Wn));                           \
} while (0)

// ------- fused persistent kernel: 48 conv WGs (8 waves) + 192 LSTM WGs ----
__global__ __launch_bounds__(512, 1) void k_net(
    const int use_b16,
    const int* __restrict__ xids, const float* __restrict__ emb1,
    const float* __restrict__ conv_w, const float* __restrict__ conv_b,
    const unsigned short* __restrict__ wb0,
    const unsigned short* __restrict__ wb1,
    unsigned short* __restrict__ x0buf, unsigned short* __restrict__ x1buf,
    const float* __restrict__ hstate, const float* __restrict__ cstate,
    const float* __restrict__ wih, const float* __restrict__ whh,
    const float* __restrict__ bih, const float* __restrict__ bhh,
    float* __restrict__ h1buf, float* __restrict__ h2buf,
    unsigned* __restrict__ cflags, unsigned* __restrict__ cepoch,
    unsigned* __restrict__ lflags, unsigned* __restrict__ lepoch,
    float* __restrict__ dout) {

    __shared__ __align__(16) unsigned short xs_hi[97 * CKP];   // 51216 B
    __shared__ __align__(16) unsigned short xs_lo[97 * CKP];   // 51216 B
    __shared__ __align__(16) float hx[EMB], hb2[EMB], ex[EMB];
    __shared__ float g1s[16], g2s[16], c1s[4], c2s[4];
    float* part = (float*)xs_hi;   // 8*1536 f32 = 49152 B, aliased (safe:
                                   // written only after last chunk consumed)

    const int tid = threadIdx.x;

    if (blockIdx.x < CONV_WG) {
        const int wv = tid >> 6;           // wave 0..7 (K-split)
        const int ln = tid & 63;
        const int lj = ln & 15;
        const int lg = ln >> 4;
        const int bI = blockIdx.x;
        const int r0 = bI * 16;

        if (use_b16) {
            bf16x8 W0a[3], W1a[3], W0b[3], W1b[3];
            ISSUE_W_B16(0, W0a, W1a);
#pragma unroll 1
            for (int lay = 0; lay + 1 < NLAYER; lay += 2) {
                CONV_LAYER_B16(lay, W0a, W1a, W0b, W1b);
                CONV_LAYER_B16(lay + 1, W0b, W1b, W0a, W1a);
            }
            CONV_LAYER_B16(NLAYER - 1, W0a, W1a, W0b, W1b);
        } else {
            float4 Wa[3][4], Wb[3][4];
            ISSUE_W_F32(0, Wa);
#pragma unroll 1
            for (int lay = 0; lay + 1 < NLAYER; lay += 2) {
                CONV_LAYER_F32(lay, Wa, Wb);
                CONV_LAYER_F32(lay + 1, Wb, Wa);
            }
            CONV_LAYER_F32(NLAYER - 1, Wa, Wb);
        }
    } else {
        // ====== LSTM path: 97 ticks, work on tid<256, extra waves idle ====
        const int wg   = blockIdx.x - CONV_WG;    // 0..191
        const bool act = tid < 256;
        const int l16  = tid & 15;
        const int r16  = (tid & 255) >> 4;
        const int gate = r16 >> 2;
        const int jl   = r16 & 3;
        const int j0   = wg * 4;
        const int grow = gate * EMB + j0 + jl;

        float wi1r[48], wh1r[48], wi2r[48], wh2r[48];
        float b1 = 0.f, b2 = 0.f;
        if (act) {
            const float* wih1 = wih;
            const float* whh1 = whh;
            const float* wih2 = wih + (size_t)G4 * EMB;
            const float* whh2 = whh + (size_t)G4 * EMB;
#pragma unroll
            for (int i = 0; i < 48; ++i) {
                const int k = l16 + (i << 4);
                wi1r[i] = wih1[(size_t)grow * EMB + k];
                wh1r[i] = whh1[(size_t)grow * EMB + k];
                wi2r[i] = wih2[(size_t)grow * EMB + k];
                wh2r[i] = whh2[(size_t)grow * EMB + k];
            }
            b1 = bih[grow] + bhh[grow];
            b2 = bih[G4 + grow] + bhh[G4 + grow];
        }

        if (tid < 4)      c1s[tid]     = cstate[j0 + tid];
        else if (tid < 8) c2s[tid - 4] = cstate[EMB + j0 + (tid - 4)];
        __syncthreads();

        for (int T = 0; T <= SEQ; ++T) {
            if (tid < 192) {
                if (T < SEQ) {     // emb1 staging: plain cached loads
                    const int tok = xids[T];
                    float4 v = *(const float4*)(emb1 + (size_t)tok * EMB + tid * 4);
                    *(float4*)(ex + tid * 4) = v;
                }
                ull a0, a1;
                if (T == 0) {
                    a0 = ld64g(hstate + tid * 4);
                    a1 = ld64g(hstate + tid * 4 + 2);
                } else {
                    a0 = ld64g(h1buf + (T - 1) * EMB + tid * 4);
                    a1 = ld64g(h1buf + (T - 1) * EMB + tid * 4 + 2);
                }
                *(ull*)(hx + tid * 4)     = a0;
                *(ull*)(hx + tid * 4 + 2) = a1;
                ull b0 = 0, b1v = 0;
                if (T >= 1) {
                    if (T == 1) {
                        b0  = ld64g(hstate + EMB + tid * 4);
                        b1v = ld64g(hstate + EMB + tid * 4 + 2);
                    } else {
                        b0  = ld64g(h2buf + (T - 2) * EMB + tid * 4);
                        b1v = ld64g(h2buf + (T - 2) * EMB + tid * 4 + 2);
                    }
                }
                *(ull*)(hb2 + tid * 4)     = b0;
                *(ull*)(hb2 + tid * 4 + 2) = b1v;
            }
            __syncthreads();

            if (act && T < SEQ) {
                float a = b1;
#pragma unroll
                for (int i = 0; i < 48; ++i)
                    a = fmaf(wi1r[i], ex[l16 + (i << 4)], a);
#pragma unroll
                for (int i = 0; i < 48; ++i)
                    a = fmaf(wh1r[i], hx[l16 + (i << 4)], a);
                a = red16(a);
                if (l16 == 0) g1s[r16] = a;
            }
            if (act && T >= 1) {
                float b = b2;
#pragma unroll
                for (int i = 0; i < 48; ++i)
                    b = fmaf(wi2r[i], hx[l16 + (i << 4)], b);
#pragma unroll
                for (int i = 0; i < 48; ++i)
                    b = fmaf(wh2r[i], hb2[l16 + (i << 4)], b);
                b = red16(b);
                if (l16 == 0) g2s[r16] = b;
            }
            __syncthreads();

            if (tid < 4 && T < SEQ) {
                const int j = tid;
                const float i_ = sigmoidf_(g1s[j]);
                const float f_ = sigmoidf_(g1s[4 + j]);
                const float g_ = tanhf(g1s[8 + j]);
                const float o_ = sigmoidf_(g1s[12 + j]);
                const float c  = f_ * c1s[j] + i_ * g_;
                c1s[j] = c;
                const float h = o_ * tanhf(c);
                stf32g(&h1buf[T * EMB + j0 + j], h);
                if (T == SEQ - 1) {
                    dout[1 + j0 + j]    = h;   // h[0]
                    dout[1537 + j0 + j] = c;   // c[0]
                }
            } else if (tid >= 4 && tid < 8 && T >= 1) {
                const int j = tid - 4;
                const int s = T - 1;
                const float i_ = sigmoidf_(g2s[j]);
                const float f_ = sigmoidf_(g2s[4 + j]);
                const float g_ = tanhf(g2s[8 + j]);
                const float o_ = sigmoidf_(g2s[12 + j]);
                const float c  = f_ * c2s[j] + i_ * g_;
                c2s[j] = c;
                const float h = o_ * tanhf(c);
                stf32g(&h2buf[s * EMB + j0 + j], h);
                if (s == SEQ - 1) {
                    dout[1 + EMB + j0 + j]    = h;   // h[1]
                    dout[1537 + EMB + j0 + j] = c;   // c[1]
                }
            }
            if (T < SEQ)
                relbar(lflags, lepoch, LSTM_WG, wg, (unsigned)(T + 1));
        }
    }
}

// ---------------- deterministic scalar epilogue ---------------------------
__global__ void k_final(const float* __restrict__ pred_w,
                        const float* __restrict__ pred_b,
                        const float* __restrict__ m2w,
                        const float* __restrict__ m2b,
                        const float* __restrict__ prev,
                        float* __restrict__ dout) {
    __shared__ float red[256];
    const int tid = threadIdx.x;
    float p1 = 0.f;
    for (int idx = tid; idx < 2 * EMB; idx += 256) {
        const int l = idx / EMB;
        const int j = idx - l * EMB;
        p1 += dout[1537 + idx] * pred_w[j * 2 + l];
    }
    float p2 = 0.f;
    for (int e = tid; e < EMB; e += 256)
        p2 += dout[3074 + e] * m2w[2 * e] + prev[e] * m2w[2 * e + 1];

    red[tid] = p1;
    __syncthreads();
    for (int s = 128; s > 0; s >>= 1) {
        if (tid < s) red[tid] += red[tid + s];
        __syncthreads();
    }
    if (tid == 0) dout[0] = red[0] + pred_b[0];
    __syncthreads();
    red[tid] = p2;
    __syncthreads();
    for (int s = 128; s > 0; s >>= 1) {
        if (tid < s) red[tid] += red[tid + s];
        __syncthreads();
    }
    if (tid == 0) dout[3073] = red[0] + m2b[0];
}

extern "C" void kernel_launch(void* const* d_in, const int* in_sizes, int n_in,
                              void* d_out, int out_size, void* d_ws, size_t ws_size,
                              hipStream_t stream) {
    const int*   x      = (const int*)d_in[0];
    const float* hstate = (const float*)d_in[1];
    const float* cstate = (const float*)d_in[2];
    const float* prev   = (const float*)d_in[3];
    const float* emb1   = (const float*)d_in[4];
    const float* emb2   = (const float*)d_in[5];
    const float* wih    = (const float*)d_in[6];
    const float* whh    = (const float*)d_in[7];
    const float* bih    = (const float*)d_in[8];
    const float* bhh    = (const float*)d_in[9];
    const float* predw  = (const float*)d_in[10];
    const float* predb  = (const float*)d_in[11];
    const float* convw  = (const float*)d_in[12];
    const float* convb  = (const float*)d_in[13];
    const float* m2w    = (const float*)d_in[14];
    const float* m2b    = (const float*)d_in[15];
    float* out = (float*)d_out;

    // ws layout (bytes): [0,32768) flags; then h1,h2 (f32), x0,x1 (u16),
    // then wb0, wb1 bf16 weight planes (if ws_size allows).
    char* wsb = (char*)d_ws;
    unsigned* wsw = (unsigned*)d_ws;
    unsigned* cflags = wsw;            // words [0 .. 768)
    unsigned* cepoch = wsw + 1024;     // 32 replicas
    unsigned* lflags = wsw + 2048;     // 192 x stride16
    unsigned* lepoch = wsw + 6144;     // 32 replicas
    float* h1buf = (float*)(wsb + 32768);                       // 294912 B
    float* h2buf = (float*)(wsb + 32768 + 294912);              // 294912 B
    unsigned short* x0buf = (unsigned short*)(wsb + 622592);    // 294912 B
    unsigned short* x1buf = (unsigned short*)(wsb + 917504);    // 294912 B
    unsigned short* wb0   = (unsigned short*)(wsb + 1212416);   // 112066560 B
    unsigned short* wb1   = (unsigned short*)(wsb + 113278976); // 112066560 B
    const int use_b16 = (ws_size >= WB_BYTES) ? 1 : 0;

    hipMemsetAsync(d_ws, 0, 32768, stream);
    hipMemsetAsync(d_out, 0, out_size * sizeof(float), stream);

    if (use_b16)
        k_prep<<<54720, 256, 0, stream>>>(convw, wb0, wb1);
    k_embed<<<96, 256, 0, stream>>>(x, emb2, x0buf);
    k_net<<<CONV_WG + LSTM_WG, 512, 0, stream>>>(
        use_b16, x, emb1, convw, convb, wb0, wb1, x0buf, x1buf,
        hstate, cstate, wih, whh, bih, bhh, h1buf, h2buf,
        cflags, cepoch, lflags, lepoch, out);
    k_final<<<1, 256, 0, stream>>>(predw, predb, m2w, m2b, prev, out);
}

// Round 19
// 944.052 us; speedup vs baseline: 2.5806x; 1.0071x over previous
//
#include <hip/hip_runtime.h>
#include <math.h>

#define SEQ 96
#define EMB 768
#define G4  3072   // 4*H
#define NLAYER 95  // conv layers
#define CKP 264    // xs col pitch (bf16 elems): 256 k-chunk + 8 pad
#define CONV_WG 64   // 64 WGs x 12-row slabs (64+192 = 256 CUs exact)
#define LSTM_WG 192
#define NREP 32      // epoch replica lines
#define XPITCH 1536  // ushorts per col in x buffers: 48 blocks x (hi16|lo16)
#define WB_BYTES 225345536ull   // ws bytes needed for bf16 weight planes path

typedef float  f32x4  __attribute__((ext_vector_type(4)));
typedef short  bf16x8 __attribute__((ext_vector_type(8)));
typedef unsigned long long ull;

union BF8 { unsigned short u[8]; bf16x8 v; };

__device__ __forceinline__ unsigned short f2bf(float f) {   // RNE fp32->bf16
    unsigned u = __float_as_uint(f);
    u += 0x7FFFu + ((u >> 16) & 1u);
    return (unsigned short)(u >> 16);
}
__device__ __forceinline__ float bf2f(unsigned short u) {
    return __uint_as_float(((unsigned)u) << 16);
}

// ---- sc1 stores for cross-WG mutable data; consumers use plain loads +
// ---- buffer_inv (conv) or sc1 loads (LSTM).
__device__ __forceinline__ ull ld64g(const void* p) {
    return __hip_atomic_load((const ull*)p, __ATOMIC_RELAXED,
                             __HIP_MEMORY_SCOPE_AGENT);
}
__device__ __forceinline__ void st32g(void* p, unsigned v) {
    __hip_atomic_store((unsigned*)p, v, __ATOMIC_RELAXED,
                       __HIP_MEMORY_SCOPE_AGENT);
}
__device__ __forceinline__ void stf32g(float* p, float v) {
    __hip_atomic_store((unsigned*)p, __float_as_uint(v), __ATOMIC_RELAXED,
                       __HIP_MEMORY_SCOPE_AGENT);
}
__device__ __forceinline__ unsigned ldflag(const unsigned* p) {
    return __hip_atomic_load(p, __ATOMIC_RELAXED, __HIP_MEMORY_SCOPE_AGENT);
}
__device__ __forceinline__ unsigned ldflag_acq(const unsigned* p) {
    // acquire: s_waitcnt + buffer_inv (L1/L2 invalidate, no writeback)
    return __hip_atomic_load(p, __ATOMIC_ACQUIRE, __HIP_MEMORY_SCOPE_AGENT);
}
__device__ __forceinline__ void stflag(unsigned* p, unsigned v) {
    __hip_atomic_store(p, v, __ATOMIC_RELAXED, __HIP_MEMORY_SCOPE_AGENT);
}

// ------ LSTM grid barrier: sc1 flags, 32 epoch replicas, no invalidates ---
__device__ __forceinline__ void relbar(unsigned* flags, unsigned* epoch,
                                       int nwg, int wg, unsigned target) {
    asm volatile("s_waitcnt vmcnt(0)" ::: "memory");
    __syncthreads();
    if (threadIdx.x == 0) stflag(&flags[wg * 16], target);
    if (wg == 0) {
        if ((int)threadIdx.x < nwg)
            while (ldflag(&flags[threadIdx.x * 16]) < target)
                __builtin_amdgcn_s_sleep(2);
        __syncthreads();
        if (threadIdx.x < NREP) stflag(&epoch[threadIdx.x * 16], target);
    }
    if (threadIdx.x == 0) {
        const unsigned* ep = &epoch[(wg & (NREP - 1)) * 16];
        while (ldflag(ep) < target)
            __builtin_amdgcn_s_sleep(8);
    }
    asm volatile("" ::: "memory");
    __syncthreads();
}

__device__ __forceinline__ float red16(float a) {
    a += __shfl_xor(a, 8, 16);
    a += __shfl_xor(a, 4, 16);
    a += __shfl_xor(a, 2, 16);
    a += __shfl_xor(a, 1, 16);
    return a;
}

__device__ __forceinline__ float sigmoidf_(float x) {
    return 1.0f / (1.0f + __expf(-x));
}

// ---- weight prep: fp32 interleaved (w0,w1) -> bf16 planes wb0, wb1 -------
__global__ void k_prep(const float* __restrict__ w,
                       unsigned short* __restrict__ wb0,
                       unsigned short* __restrict__ wb1) {
    const size_t p0 = ((size_t)blockIdx.x * 256 + threadIdx.x) * 4;
    const f32x4* src = (const f32x4*)(w + p0 * 2);
    f32x4 f0 = __builtin_nontemporal_load(src);
    f32x4 f1 = __builtin_nontemporal_load(src + 1);
    ushort4 a, b;
    a.x = f2bf(f0.x); b.x = f2bf(f0.y);
    a.y = f2bf(f0.z); b.y = f2bf(f0.w);
    a.z = f2bf(f1.x); b.z = f2bf(f1.y);
    a.w = f2bf(f1.z); b.w = f2bf(f1.w);
    *(ushort4*)(wb0 + p0) = a;
    *(ushort4*)(wb1 + p0) = b;
}

// ---------------- emb2 gather -> hi/lo bf16 x0 ----------------------------
__global__ void k_embed(const int* __restrict__ xids,
                        const float* __restrict__ emb2,
                        unsigned short* __restrict__ x0) {
    const int col = blockIdx.x;                 // 96 blocks
    const int tok = xids[col];
    const int tid = threadIdx.x;
    if (tid < 192) {
        float4 v = *(const float4*)(emb2 + (size_t)tok * EMB + tid * 4);
        ushort4 hv, lv;
        hv.x = f2bf(v.x); lv.x = f2bf(v.x - bf2f(hv.x));
        hv.y = f2bf(v.y); lv.y = f2bf(v.y - bf2f(hv.y));
        hv.z = f2bf(v.z); lv.z = f2bf(v.z - bf2f(hv.z));
        hv.w = f2bf(v.w); lv.w = f2bf(v.w - bf2f(hv.w));
        unsigned short* base = x0 + col * XPITCH + (tid >> 2) * 32 + (tid & 3) * 4;
        *(ushort4*)base        = hv;
        *(ushort4*)(base + 16) = lv;
    }
}

// ---- issue one layer's 12-row weight slab (lj<12; rows 12-15 stay 0) -----
#define ISSUE_W_B16(LAY, W0R, W1R) do {                                      \
    if (lj < 12) {                                                           \
        const unsigned short* w0_ =                                          \
            wb0 + ((size_t)(LAY) * EMB + r0 + lj) * EMB;                     \
        const unsigned short* w1_ =                                          \
            wb1 + ((size_t)(LAY) * EMB + r0 + lj) * EMB;                     \
        _Pragma("unroll")                                                    \
        for (int ch_ = 0; ch_ < 3; ++ch_) {                                  \
            const int k_ = ch_ * 256 + wv * 32 + lg * 8;                     \
            W0R[ch_] = *(const bf16x8*)(w0_ + k_);                           \
            W1R[ch_] = *(const bf16x8*)(w1_ + k_);                           \
        }                                                                    \
    }                                                                        \
} while (0)

// ---- conv barrier: in-barrier prefetch + consumer-side cache inv ---------
#define CONV_BARRIER(LAY, PREFETCH) do {                                     \
    if ((LAY) + 1 < NLAYER) {                                                \
        const unsigned tgt = (unsigned)((LAY) + 1);                          \
        asm volatile("s_waitcnt vmcnt(0)" ::: "memory");                     \
        __syncthreads();                                                     \
        if (tid == 0) stflag(&cflags[bI * 16], tgt);                         \
        PREFETCH;                                                            \
        asm volatile("" ::: "memory");                                       \
        if (bI == 0) {                                                       \
            if (tid < CONV_WG)                                               \
                while (ldflag(&cflags[tid * 16]) < tgt)                      \
                    __builtin_amdgcn_s_sleep(2);                             \
            __syncthreads();                                                 \
            if (tid < NREP) stflag(&cepoch[tid * 16], tgt);                  \
        }                                                                    \
        if (tid == 0) {                                                      \
            const unsigned* ep = &cepoch[(bI & (NREP - 1)) * 16];            \
            while (ldflag(ep) < tgt)                                         \
                __builtin_amdgcn_s_sleep(8);                                 \
            (void)ldflag_acq(ep);      /* inv L1/L2: fresh x reads */        \
        }                                                                    \
        asm volatile("" ::: "memory");                                       \
        __syncthreads();                                                     \
    }                                                                        \
} while (0)

// ---- epilogue: 12 rows (6 pairs/col), 8-way K-split reduce + relu --------
// o2 = c*6 + p (p<6, i0=2p); c = o2*683>>12 exact for o2 < 2048.
// Global row r0+i0 lands in the 48x32-short x layout at block B, pos.
#define CONV_EPILOGUE(LAY) do {                                              \
    _Pragma("unroll")                                                        \
    for (int nt = 0; nt < 6; ++nt) if (nt < nts)                             \
        *(f32x4*)&part[wv * 1536 + (nt * 16 + lj) * 16 + lg * 4] = acc[nt];  \
    __syncthreads();                                                         \
    _Pragma("unroll")                                                        \
    for (int j = 0; j < 2; ++j) {                                            \
        const int o2 = tid + j * 512;                                        \
        if (o2 < ncols * 6) {                                                \
            const int c = (o2 * 683) >> 12;                                  \
            const int p = o2 - c * 6;                                        \
            const int i0 = p * 2;                                            \
            const int oo = c * 16 + i0;                                      \
            float s0 = conv_b[(LAY) * EMB + r0 + i0];                        \
            float s1 = conv_b[(LAY) * EMB + r0 + i0 + 1];                    \
            _Pragma("unroll")                                                \
            for (int w = 0; w < 8; ++w) {                                    \
                s0 += part[w * 1536 + oo];                                   \
                s1 += part[w * 1536 + oo + 1];                               \
            }                                                                \
            s0 = fmaxf(s0, 0.f); s1 = fmaxf(s1, 0.f);                        \
            const unsigned short h0 = f2bf(s0), h1 = f2bf(s1);               \
            const unsigned short l0 = f2bf(s0 - bf2f(h0));                   \
            const unsigned short l1 = f2bf(s1 - bf2f(h1));                   \
            const int rg = r0 + i0;                                          \
            unsigned short* dp = dst + c * XPITCH + ((rg >> 4) << 5)         \
                                     + (rg & 15);                            \
            st32g(dp,      (unsigned)h0 | ((unsigned)h1 << 16));             \
            st32g(dp + 16, (unsigned)l0 | ((unsigned)l1 << 16));             \
            if ((LAY) == NLAYER - 1 && c == 0) {                             \
                dout[3074 + rg]     = s0;                                    \
                dout[3074 + rg + 1] = s1;                                    \
            }                                                                \
        }                                                                    \
    }                                                                        \
} while (0)

// ---- x-chunk restage: plain COALESCED 16B loads (inv-protected) -> LDS ---
#define STAGE_X(CH) do {                                                     \
    _Pragma("unroll")                                                        \
    for (int j = 0; j < 6; ++j) {                                            \
        const int u = tid + j * 512;                                         \
        const int c = u >> 5, q = u & 31;                                    \
        if (c < scols) {                                                     \
            const int k = (CH) * 256 + q * 8;                                \
            const unsigned short* sp =                                       \
                src + c * XPITCH + ((k >> 4) << 5) + (k & 15);               \
            bf16x8 vh = *(const bf16x8*)sp;          /* dwordx4 */           \
            bf16x8 vl = *(const bf16x8*)(sp + 16);   /* dwordx4 */           \
            *(bf16x8*)(xs_hi + c * CKP + q * 8) = vh;                        \
            *(bf16x8*)(xs_lo + c * CKP + q * 8) = vl;                        \
        }                                                                    \
    }                                                                        \
} while (0)

// ---- one chunk's MFMA work (1 Ktile per wave), bf16 weight regs ----------
#define CONV_CHUNK_B16(CH, W0c, W1c) do {                                    \
    const bf16x8 a0 = W0c[CH];                                               \
    const bf16x8 a1 = W1c[CH];                                               \
    const int klocal = wv * 32;                                              \
    _Pragma("unroll")                                                        \
    for (int nt = 0; nt < 6; ++nt) if (nt < nts) {                           \
        const int co = (nt * 16 + lj) * CKP + klocal + lg * 8;               \
        bf16x8 bh0 = *(const bf16x8*)(xs_hi + co);                           \
        bf16x8 bl0 = *(const bf16x8*)(xs_lo + co);                           \
        bf16x8 bh1 = *(const bf16x8*)(xs_hi + co + CKP);                     \
        bf16x8 bl1 = *(const bf16x8*)(xs_lo + co + CKP);                     \
        acc[nt] = __builtin_amdgcn_mfma_f32_16x16x32_bf16(                   \
                      a0, bh0, acc[nt], 0, 0, 0);                            \
        acc[nt] = __builtin_amdgcn_mfma_f32_16x16x32_bf16(                   \
                      a0, bl0, acc[nt], 0, 0, 0);                            \
        acc[nt] = __builtin_amdgcn_mfma_f32_16x16x32_bf16(                   \
                      a1, bh1, acc[nt], 0, 0, 0);                            \
        acc[nt] = __builtin_amdgcn_mfma_f32_16x16x32_bf16(                   \
                      a1, bl1, acc[nt], 0, 0, 0);                            \
    }                                                                        \
} while (0)

// ---- full conv layer, bf16 weight planes ---------------------------------
#define CONV_LAYER_B16(LAY, W0c, W1c, W0n, W1n) do {                         \
    const int ncols = NLAYER - (LAY);                                        \
    const int scols = (ncols + 1 < 96) ? ncols + 1 : 96;                     \
    const int nts   = (ncols + 15) >> 4;                                     \
    const unsigned short* src = ((LAY) & 1) ? x1buf : x0buf;                 \
    unsigned short*       dst = ((LAY) & 1) ? x0buf : x1buf;                 \
    f32x4 acc[6];                                                            \
    _Pragma("unroll")                                                        \
    for (int n = 0; n < 6; ++n) acc[n] = (f32x4)0.f;                         \
    _Pragma("unroll")                                                        \
    for (int ch = 0; ch < 3; ++ch) {                                         \
        STAGE_X(ch);                                                         \
        __syncthreads();                                                     \
        CONV_CHUNK_B16(ch, W0c, W1c);                                        \
        __syncthreads();                                                     \
    }                                                                        \
    CONV_EPILOGUE(LAY);                                                      \
    CONV_BARRIER(LAY, ISSUE_W_B16((LAY) + 1, W0n, W1n));                     \
} while (0)

// ---- fp32 fallback: 12-row weight slab in float4 regs (8-wave split) -----
#define ISSUE_W_F32(LAY, WREG) do {                                          \
    if (lj < 12) {                                                           \
        const float* wsl_ = conv_w + (size_t)(LAY) * (EMB * EMB * 2)         \
                                   + (size_t)(r0 + lj) * (EMB * 2);          \
        _Pragma("unroll")                                                    \
        for (int ch_ = 0; ch_ < 3; ++ch_) {                                  \
            const int K0_ = ch_ * 256 + wv * 32;                             \
            const float4* ap_ =                                              \
                (const float4*)(wsl_ + (size_t)(K0_ + lg * 8) * 2);          \
            _Pragma("unroll")                                                \
            for (int j_ = 0; j_ < 4; ++j_) WREG[ch_][j_] = ap_[j_];          \
        }                                                                    \
    }                                                                        \
} while (0)

#define CONV_LAYER_F32(LAY, Wc, Wn) do {                                     \
    const int ncols = NLAYER - (LAY);                                        \
    const int scols = (ncols + 1 < 96) ? ncols + 1 : 96;                     \
    const int nts   = (ncols + 15) >> 4;                                     \
    const unsigned short* src = ((LAY) & 1) ? x1buf : x0buf;                 \
    unsigned short*       dst = ((LAY) & 1) ? x0buf : x1buf;                 \
    f32x4 acc[6];                                                            \
    _Pragma("unroll")                                                        \
    for (int n = 0; n < 6; ++n) acc[n] = (f32x4)0.f;                         \
    _Pragma("unroll")                                                        \
    for (int ch = 0; ch < 3; ++ch) {                                         \
        STAGE_X(ch);                                                         \
        __syncthreads();                                                     \
        {                                                                    \
            BF8 a0h, a0l, a1h, a1l;                                          \
            _Pragma("unroll")                                                \
            for (int d = 0; d < 8; ++d) {                                    \
                const float4 f = Wc[ch][d >> 1];                             \
                const float w0 = (d & 1) ? f.z : f.x;                        \
                const float w1 = (d & 1) ? f.w : f.y;                        \
                const unsigned short h0 = f2bf(w0);                          \
                const unsigned short h1 = f2bf(w1);                          \
                a0h.u[d] = h0; a0l.u[d] = f2bf(w0 - bf2f(h0));               \
                a1h.u[d] = h1; a1l.u[d] = f2bf(w1 - bf2f(h1));               \
            }                                                                \
            const int klocal = wv * 32;                                      \
            _Pragma("unroll")                                                \
            for (int nt = 0; nt < 6; ++nt) if (nt < nts) {                   \
                const int co = (nt * 16 + lj) * CKP + klocal + lg * 8;       \
                bf16x8 bh0 = *(const bf16x8*)(xs_hi + co);                   \
                bf16x8 bl0 = *(const bf16x8*)(xs_lo + co);                   \
                bf16x8 bh1 = *(const bf16x8*)(xs_hi + co + CKP);             \
                bf16x8 bl1 = *(const bf16x8*)(xs_lo + co + CKP);             \
                acc[nt] = __builtin_amdgcn_mfma_f32_16x16x32_bf16(           \
                              a0h.v, bh0, acc[nt], 0, 0, 0);                 \
                acc[nt] = __builtin_amdgcn_mfma_f32_16x16x32_bf16(           \
                              a0h.v, bl0, acc[nt], 0, 0, 0);                 \
                acc[nt] = __builtin_amdgcn_mfma_f32_16x16x32_bf16(           \
                              a0l.v, bh0, acc[nt], 0, 0, 0);                 \
                acc[nt] = __builtin_amdgcn_mfma_f32_16x16x32_bf16(           \
                              a1h.v, bh1, acc[nt], 0, 0, 0);                 \
                acc[nt] = __builtin_amdgcn_mfma_f32_16x16x32_bf16(           \
                              a1h.v, bl1, acc[nt], 0, 0, 0);                 \
                acc[nt] = __builtin_amdgcn_mfma_f32_16x16x32_bf16(           \
                              a1l.v, bh1, acc[nt], 0, 0, 0);                 \
            }                                                                \
        }                                                                    \
        __syncthreads();                                                     \
    }                                                                        \
    CONV_EPILOGUE(LAY);                                                      \
    CONV_BARRIER(LAY, ISSUE_W_F32((LAY) + 1, Wn));                           \
} while (0)

// ------- fused persistent kernel: 64 conv WGs (8 waves) + 192 LSTM WGs ----
__global__ __launch_bounds__(512, 1) void k_net(
    const int use_b16,
    const int* __restrict__ xids, const float* __restrict__ emb1,
    const float* __restrict__ conv_w, const float* __restrict__ conv_b,
    const unsigned short* __restrict__ wb0,
    const unsigned short* __restrict__ wb1,
    unsigned short* __restrict__ x0buf, unsigned short* __restrict__ x1buf,
    const float* __restrict__ hstate, const float* __restrict__ cstate,
    const float* __restrict__ wih, const float* __restrict__ whh,
    const float* __restrict__ bih, const float* __restrict__ bhh,
    float* __restrict__ h1buf, float* __restrict__ h2buf,
    unsigned* __restrict__ cflags, unsigned* __restrict__ cepoch,
    unsigned* __restrict__ lflags, unsigned* __restrict__ lepoch,
    float* __restrict__ dout) {

    __shared__ __align__(16) unsigned short xs_hi[97 * CKP];   // 51216 B
    __shared__ __align__(16) unsigned short xs_lo[97 * CKP];   // 51216 B
    __shared__ __align__(16) float hx[EMB], hb2[EMB], ex[EMB];
    __shared__ float g1s[16], g2s[16], c1s[4], c2s[4];
    float* part = (float*)xs_hi;   // 8*1536 f32 = 49152 B, aliased (safe:
                                   // written only after last chunk consumed)

    const int tid = threadIdx.x;

    if (blockIdx.x < CONV_WG) {
        const int wv = tid >> 6;           // wave 0..7 (K-split)
        const int ln = tid & 63;
        const int lj = ln & 15;
        const int lg = ln >> 4;
        const int bI = blockIdx.x;
        const int r0 = bI * 12;            // 12-row slab

        if (use_b16) {
            BF8 zz;
#pragma unroll
            for (int d = 0; d < 8; ++d) zz.u[d] = 0;
            bf16x8 W0a[3], W1a[3], W0b[3], W1b[3];
#pragma unroll
            for (int c = 0; c < 3; ++c) {
                W0a[c] = zz.v; W1a[c] = zz.v;
                W0b[c] = zz.v; W1b[c] = zz.v;
            }
            ISSUE_W_B16(0, W0a, W1a);
#pragma unroll 1
            for (int lay = 0; lay + 1 < NLAYER; lay += 2) {
                CONV_LAYER_B16(lay, W0a, W1a, W0b, W1b);
                CONV_LAYER_B16(lay + 1, W0b, W1b, W0a, W1a);
            }
            CONV_LAYER_B16(NLAYER - 1, W0a, W1a, W0b, W1b);
        } else {
            float4 Wa[3][4], Wb[3][4];
#pragma unroll
            for (int c = 0; c < 3; ++c)
#pragma unroll
                for (int j = 0; j < 4; ++j) {
                    Wa[c][j] = make_float4(0.f, 0.f, 0.f, 0.f);
                    Wb[c][j] = make_float4(0.f, 0.f, 0.f, 0.f);
                }
            ISSUE_W_F32(0, Wa);
#pragma unroll 1
            for (int lay = 0; lay + 1 < NLAYER; lay += 2) {
                CONV_LAYER_F32(lay, Wa, Wb);
                CONV_LAYER_F32(lay + 1, Wb, Wa);
            }
            CONV_LAYER_F32(NLAYER - 1, Wa, Wb);
        }
    } else {
        // ====== LSTM path: 97 ticks, work on tid<256, extra waves idle ====
        const int wg   = blockIdx.x - CONV_WG;    // 0..191
        const bool act = tid < 256;
        const int l16  = tid & 15;
        const int r16  = (tid & 255) >> 4;
        const int gate = r16 >> 2;
        const int jl   = r16 & 3;
        const int j0   = wg * 4;
        const int grow = gate * EMB + j0 + jl;

        float wi1r[48], wh1r[48], wi2r[48], wh2r[48];
        float b1 = 0.f, b2 = 0.f;
        if (act) {
            const float* wih1 = wih;
            const float* whh1 = whh;
            const float* wih2 = wih + (size_t)G4 * EMB;
            const float* whh2 = whh + (size_t)G4 * EMB;
#pragma unroll
            for (int i = 0; i < 48; ++i) {
                const int k = l16 + (i << 4);
                wi1r[i] = wih1[(size_t)grow * EMB + k];
                wh1r[i] = whh1[(size_t)grow * EMB + k];
                wi2r[i] = wih2[(size_t)grow * EMB + k];
                wh2r[i] = whh2[(size_t)grow * EMB + k];
            }
            b1 = bih[grow] + bhh[grow];
            b2 = bih[G4 + grow] + bhh[G4 + grow];
        }

        if (tid < 4)      c1s[tid]     = cstate[j0 + tid];
        else if (tid < 8) c2s[tid - 4] = cstate[EMB + j0 + (tid - 4)];
        __syncthreads();

        for (int T = 0; T <= SEQ; ++T) {
            if (tid < 192) {
                if (T < SEQ) {     // emb1 staging: plain cached loads
                    const int tok = xids[T];
                    float4 v = *(const float4*)(emb1 + (size_t)tok * EMB + tid * 4);
                    *(float4*)(ex + tid * 4) = v;
                }
                ull a0, a1;
                if (T == 0) {
                    a0 = ld64g(hstate + tid * 4);
                    a1 = ld64g(hstate + tid * 4 + 2);
                } else {
                    a0 = ld64g(h1buf + (T - 1) * EMB + tid * 4);
                    a1 = ld64g(h1buf + (T - 1) * EMB + tid * 4 + 2);
                }
                *(ull*)(hx + tid * 4)     = a0;
                *(ull*)(hx + tid * 4 + 2) = a1;
                ull b0 = 0, b1v = 0;
                if (T >= 1) {
                    if (T == 1) {
                        b0  = ld64g(hstate + EMB + tid * 4);
                        b1v = ld64g(hstate + EMB + tid * 4 + 2);
                    } else {
                        b0  = ld64g(h2buf + (T - 2) * EMB + tid * 4);
                        b1v = ld64g(h2buf + (T - 2) * EMB + tid * 4 + 2);
                    }
                }
                *(ull*)(hb2 + tid * 4)     = b0;
                *(ull*)(hb2 + tid * 4 + 2) = b1v;
            }
            __syncthreads();

            if (act && T < SEQ) {
                float a = b1;
#pragma unroll
                for (int i = 0; i < 48; ++i)
                    a = fmaf(wi1r[i], ex[l16 + (i << 4)], a);
#pragma unroll
                for (int i = 0; i < 48; ++i)
                    a = fmaf(wh1r[i], hx[l16 + (i << 4)], a);
                a = red16(a);
                if (l16 == 0) g1s[r16] = a;
            }
            if (act && T >= 1) {
                float b = b2;
#pragma unroll
                for (int i = 0; i < 48; ++i)
                    b = fmaf(wi2r[i], hx[l16 + (i << 4)], b);
#pragma unroll
                for (int i = 0; i < 48; ++i)
                    b = fmaf(wh2r[i], hb2[l16 + (i << 4)], b);
                b = red16(b);
                if (l16 == 0) g2s[r16] = b;
            }
            __syncthreads();

            if (tid < 4 && T < SEQ) {
                const int j = tid;
                const float i_ = sigmoidf_(g1s[j]);
                const float f_ = sigmoidf_(g1s[4 + j]);
                const float g_ = tanhf(g1s[8 + j]);
                const float o_ = sigmoidf_(g1s[12 + j]);
                const float c  = f_ * c1s[j] + i_ * g_;
                c1s[j] = c;
                const float h = o_ * tanhf(c);
                stf32g(&h1buf[T * EMB + j0 + j], h);
                if (T == SEQ - 1) {
                    dout[1 + j0 + j]    = h;   // h[0]
                    dout[1537 + j0 + j] = c;   // c[0]
                }
            } else if (tid >= 4 && tid < 8 && T >= 1) {
                const int j = tid - 4;
                const int s = T - 1;
                const float i_ = sigmoidf_(g2s[j]);
                const float f_ = sigmoidf_(g2s[4 + j]);
                const float g_ = tanhf(g2s[8 + j]);
                const float o_ = sigmoidf_(g2s[12 + j]);
                const float c  = f_ * c2s[j] + i_ * g_;
                c2s[j] = c;
                const float h = o_ * tanhf(c);
                stf32g(&h2buf[s * EMB + j0 + j], h);
                if (s == SEQ - 1) {
                    dout[1 + EMB + j0 + j]    = h;   // h[1]
                    dout[1537 + EMB + j0 + j] = c;   // c[1]
                }
            }
            if (T < SEQ)
                relbar(lflags, lepoch, LSTM_WG, wg, (unsigned)(T + 1));
        }
    }
}

// ---------------- deterministic scalar epilogue ---------------------------
__global__ void k_final(const float* __restrict__ pred_w,
                        const float* __restrict__ pred_b,
                        const float* __restrict__ m2w,
                        const float* __restrict__ m2b,
                        const float* __restrict__ prev,
                        float* __restrict__ dout) {
    __shared__ float red[256];
    const int tid = threadIdx.x;
    float p1 = 0.f;
    for (int idx = tid; idx < 2 * EMB; idx += 256) {
        const int l = idx / EMB;
        const int j = idx - l * EMB;
        p1 += dout[1537 + idx] * pred_w[j * 2 + l];
    }
    float p2 = 0.f;
    for (int e = tid; e < EMB; e += 256)
        p2 += dout[3074 + e] * m2w[2 * e] + prev[e] * m2w[2 * e + 1];

    red[tid] = p1;
    __syncthreads();
    for (int s = 128; s > 0; s >>= 1) {
        if (tid < s) red[tid] += red[tid + s];
        __syncthreads();
    }
    if (tid == 0) dout[0] = red[0] + pred_b[0];
    __syncthreads();
    red[tid] = p2;
    __syncthreads();
    for (int s = 128; s > 0; s >>= 1) {
        if (tid < s) red[tid] += red[tid + s];
        __syncthreads();
    }
    if (tid == 0) dout[3073] = red[0] + m2b[0];
}

extern "C" void kernel_launch(void* const* d_in, const int* in_sizes, int n_in,
                              void* d_out, int out_size, void* d_ws, size_t ws_size,
                              hipStream_t stream) {
    const int*   x      = (const int*)d_in[0];
    const float* hstate = (const float*)d_in[1];
    const float* cstate = (const float*)d_in[2];
    const float* prev   = (const float*)d_in[3];
    const float* emb1   = (const float*)d_in[4];
    const float* emb2   = (const float*)d_in[5];
    const float* wih    = (const float*)d_in[6];
    const float* whh    = (const float*)d_in[7];
    const float* bih    = (const float*)d_in[8];
    const float* bhh    = (const float*)d_in[9];
    const float* predw  = (const float*)d_in[10];
    const float* predb  = (const float*)d_in[11];
    const float* convw  = (const float*)d_in[12];
    const float* convb  = (const float*)d_in[13];
    const float* m2w    = (const float*)d_in[14];
    const float* m2b    = (const float*)d_in[15];
    float* out = (float*)d_out;

    // ws layout (bytes): [0,32768) flags; then h1,h2 (f32), x0,x1 (u16),
    // then wb0, wb1 bf16 weight planes (if ws_size allows).
    char* wsb = (char*)d_ws;
    unsigned* wsw = (unsigned*)d_ws;
    unsigned* cflags = wsw;            // 64 x stride16
    unsigned* cepoch = wsw + 1024;     // 32 replicas
    unsigned* lflags = wsw + 2048;     // 192 x stride16
    unsigned* lepoch = wsw + 6144;     // 32 replicas
    float* h1buf = (float*)(wsb + 32768);                       // 294912 B
    float* h2buf = (float*)(wsb + 32768 + 294912);              // 294912 B
    unsigned short* x0buf = (unsigned short*)(wsb + 622592);    // 294912 B
    unsigned short* x1buf = (unsigned short*)(wsb + 917504);    // 294912 B
    unsigned short* wb0   = (unsigned short*)(wsb + 1212416);   // 112066560 B
    unsigned short* wb1   = (unsigned short*)(wsb + 113278976); // 112066560 B
    const int use_b16 = (ws_size >= WB_BYTES) ? 1 : 0;

    hipMemsetAsync(d_ws, 0, 32768, stream);
    hipMemsetAsync(d_out, 0, out_size * sizeof(float), stream);

    if (use_b16)
        k_prep<<<54720, 256, 0, stream>>>(convw, wb0, wb1);
    k_embed<<<96, 256, 0, stream>>>(x, emb2, x0buf);
    k_net<<<CONV_WG + LSTM_WG, 512, 0, stream>>>(
        use_b16, x, emb1, convw, convb, wb0, wb1, x0buf, x1buf,
        hstate, cstate, wih, whh, bih, bhh, h1buf, h2buf,
        cflags, cepoch, lflags, lepoch, out);
    k_final<<<1, 256, 0, stream>>>(predw, predb, m2w, m2b, prev, out);
}